// Round 8
// baseline (462.180 us; speedup 1.0000x reference)
//
#include <hip/hip_runtime.h>
#include <stdint.h>

// Problem constants (Gemma3 attention block)
#define T_TOK 4096
#define DM    2560
#define NQ    8
#define NKV   4
#define HD    256
#define WIN   1024

using bf16x8 = __attribute__((ext_vector_type(8))) short;
using f32x4  = __attribute__((ext_vector_type(4))) float;
typedef unsigned short u16;

__device__ __forceinline__ u16 f2bf(float x) {
  union { float f; uint32_t u; } v; v.f = x;
  uint32_t u = v.u;
  return (u16)((u + 0x7fffu + ((u >> 16) & 1u)) >> 16);  // RNE
}
__device__ __forceinline__ float bf2f(u16 b) {
  union { uint32_t u; float f; } v; v.u = ((uint32_t)b) << 16;
  return v.f;
}

// async global->LDS, 16B per lane. LDS dest is wave-uniform base; HW adds lane*16.
__device__ __forceinline__ void async_cp16(const void* g, void* lds) {
  __builtin_amdgcn_global_load_lds(
      (const __attribute__((address_space(1))) uint32_t*)(uintptr_t)g,
      (__attribute__((address_space(3))) uint32_t*)(uint32_t)(uintptr_t)lds,
      16, 0, 0);
}

// ---------------------------------------------------------------------------
// f32 -> bf16 elementwise convert (vectorized float4 loads)
__global__ __launch_bounds__(256) void convert_f32_bf16(
    const float* __restrict__ in, u16* __restrict__ out, int n)
{
  for (int i = (blockIdx.x * 256 + threadIdx.x) * 4; i < n; i += gridDim.x * 256 * 4) {
    float4 v = *(const float4*)(in + i);
    ushort4 o;
    o.x = f2bf(v.x); o.y = f2bf(v.y); o.z = f2bf(v.z); o.w = f2bf(v.w);
    *(ushort4*)(out + i) = o;
  }
}

// ---------------------------------------------------------------------------
// Tiled transpose + convert: in f32 (R x C) row-major -> out bf16 (C x R)
__global__ __launch_bounds__(256) void transpose_f32_bf16(
    const float* __restrict__ in, u16* __restrict__ out, int R, int C)
{
  __shared__ u16 tile[64][65];
  const int r0 = blockIdx.y * 64, c0 = blockIdx.x * 64;
  const int tr = threadIdx.x >> 6, tc = threadIdx.x & 63;
  #pragma unroll
  for (int i = 0; i < 16; ++i) {
    int r = tr + i * 4;
    tile[r][tc] = f2bf(in[(size_t)(r0 + r) * C + c0 + tc]);
  }
  __syncthreads();
  #pragma unroll
  for (int i = 0; i < 16; ++i) {
    int c = tr + i * 4;
    out[(size_t)(c0 + c) * R + r0 + tc] = tile[tc][c];
  }
}

// ---------------------------------------------------------------------------
// 256x256 bf16 GEMM, counted-vmcnt double-buffered pipeline.
// C(MxN) = A(MxK,row-major,lda) * B^T, B is (N x K,row-major,ldb).
// 8 waves (2Mx4N), BK=64, LDS 128 KiB. 1D grid, XCD-aware swizzle (GY=16).
template<bool F32OUT>
__global__ __launch_bounds__(512, 2) void gemm256(
    const u16* __restrict__ A, const u16* __restrict__ B, void* __restrict__ Cv,
    int Kd, int lda, int ldb, int ldc)
{
  __shared__ __align__(16) u16 lds[2][2][256 * 64];  // [buf][A|B] 128 KiB
  const int tid = threadIdx.x;
  const int wave = tid >> 6, lane = tid & 63;
  const int lg = lane >> 4, lc = lane & 15;
  const int wr = wave >> 2, wc = wave & 3;  // 2 x 4 wave grid
  // XCD swizzle: consecutive remapped ids cluster on one XCD, column-major
  const int nwg = gridDim.x, bid = blockIdx.x;
  const int nid = (bid & 7) * (nwg >> 3) + (bid >> 3);
  const int m0 = (nid & 15) * 256, n0 = (nid >> 4) * 256;
  const int NT = Kd >> 6;

  const int srow = tid >> 3;
  const int scol = ((tid & 7) * 16) ^ ((srow & 7) << 4);  // pre-swizzled source col
  const u16* Ag = A + (size_t)(m0 + srow) * lda + (scol >> 1);
  const u16* Bg = B + (size_t)(n0 + srow) * ldb + (scol >> 1);
  char* ldsA0 = (char*)&lds[0][0][0];
  char* ldsB0 = (char*)&lds[0][1][0];
  char* ldsA1 = (char*)&lds[1][0][0];
  char* ldsB1 = (char*)&lds[1][1][0];

  #define STAGE256(LA, LB, KT) do {                                         \
    const int kc_ = (KT) * 64;                                              \
    _Pragma("unroll")                                                       \
    for (int li = 0; li < 4; ++li)                                          \
      async_cp16(Ag + (size_t)(li * 64) * lda + kc_, (LA) + li * 8192 + wave * 1024); \
    _Pragma("unroll")                                                       \
    for (int li = 0; li < 4; ++li)                                          \
      async_cp16(Bg + (size_t)(li * 64) * ldb + kc_, (LB) + li * 8192 + wave * 1024); \
  } while (0)

  const f32x4 zf = {0.f, 0.f, 0.f, 0.f};
  f32x4 acc[8][4];
  #pragma unroll
  for (int i = 0; i < 8; ++i)
    #pragma unroll
    for (int j = 0; j < 4; ++j) acc[i][j] = zf;

  STAGE256(ldsA0, ldsB0, 0);
  STAGE256(ldsA1, ldsB1, 1);
  asm volatile("s_waitcnt vmcnt(8)" ::: "memory");
  __builtin_amdgcn_s_barrier();
  __builtin_amdgcn_sched_barrier(0);

  for (int t = 0; t < NT; ++t) {
    const int cur = t & 1;
    const u16* Ab = &lds[cur][0][0];
    const u16* Bb = &lds[cur][1][0];

    bf16x8 bf[4][2];
    #pragma unroll
    for (int j = 0; j < 4; ++j)
      #pragma unroll
      for (int k2 = 0; k2 < 2; ++k2) {
        const int row = wc * 64 + j * 16 + lc;
        const int cb = k2 * 64 + lg * 16;
        bf[j][k2] = *(const bf16x8*)((const char*)Bb + row * 128 + (cb ^ ((row & 7) << 4)));
      }

    #pragma unroll
    for (int p = 0; p < 4; ++p) {
      bf16x8 af[2][2];
      #pragma unroll
      for (int im = 0; im < 2; ++im)
        #pragma unroll
        for (int k2 = 0; k2 < 2; ++k2) {
          const int row = wr * 128 + (p * 2 + im) * 16 + lc;
          const int cb = k2 * 64 + lg * 16;
          af[im][k2] = *(const bf16x8*)((const char*)Ab + row * 128 + (cb ^ ((row & 7) << 4)));
        }
      __builtin_amdgcn_s_setprio(1);
      #pragma unroll
      for (int im = 0; im < 2; ++im)
        #pragma unroll
        for (int j = 0; j < 4; ++j)
          #pragma unroll
          for (int k2 = 0; k2 < 2; ++k2)
            acc[p * 2 + im][j] = __builtin_amdgcn_mfma_f32_16x16x32_bf16(
                af[im][k2], bf[j][k2], acc[p * 2 + im][j], 0, 0, 0);
      __builtin_amdgcn_s_setprio(0);
    }

    __builtin_amdgcn_s_barrier();
    __builtin_amdgcn_sched_barrier(0);
    int nk = t + 2; if (nk > NT - 1) nk = NT - 1;
    if (cur == 0) { STAGE256(ldsA0, ldsB0, nk); } else { STAGE256(ldsA1, ldsB1, nk); }
    asm volatile("s_waitcnt vmcnt(8)" ::: "memory");
    __builtin_amdgcn_s_barrier();
    __builtin_amdgcn_sched_barrier(0);
  }
  #undef STAGE256

  #pragma unroll
  for (int i = 0; i < 8; ++i)
    #pragma unroll
    for (int j = 0; j < 4; ++j)
      #pragma unroll
      for (int r = 0; r < 4; ++r) {
        const int row = m0 + wr * 128 + i * 16 + lg * 4 + r;
        const int col = n0 + wc * 64 + j * 16 + lc;
        if (F32OUT) ((float*)Cv)[(size_t)row * ldc + col] = acc[i][j][r];
        else        ((u16*)Cv)[(size_t)row * ldc + col] = f2bf(acc[i][j][r]);
      }
}

// ---------------------------------------------------------------------------
// Fused RMSNorm + query-scale + RoPE. Reads qkv (T x 4096 bf16):
// cols [0,2048) = q (n-major), [2048,3072) = k, [3072,4096) = v.
__global__ __launch_bounds__(256) void fuse_norm_rope(
    const u16* __restrict__ qkv, const float* __restrict__ qnw, const float* __restrict__ knw,
    const int* __restrict__ pos, u16* __restrict__ qb, u16* __restrict__ kb,
    u16* __restrict__ vb, float* __restrict__ kvout)
{
  const int t = blockIdx.x;
  const int wave = threadIdx.x >> 6, lane = threadIdx.x & 63;
  const float p = (float)pos[t];
  const float kf = 0.10381025296523007f;  // log2(10000)/128
  float s0, c0, s1, c1;
  sincosf(p * exp2f(-(float)lane * kf), &s0, &c0);
  sincosf(p * exp2f(-(float)(lane + 64) * kf), &s1, &c1);
  const u16* row = qkv + (size_t)t * 4096;

  for (int pp = 0; pp < 4; ++pp) {
    const int hr = pp * 4 + wave;  // 0..7 q, 8..11 k, 12..15 v
    if (hr >= 12) {
      const int kk = hr - 12;
      const u16* src = row + 3072 + kk * 256;
      float* dstf = kvout + (size_t)T_TOK * NKV * HD + ((size_t)t * NKV + kk) * HD;
      u16*   dstb = vb + ((size_t)t * NKV + kk) * HD;
      #pragma unroll
      for (int q4 = 0; q4 < 4; ++q4) {
        const u16 s = src[lane + q4 * 64];
        dstf[lane + q4 * 64] = bf2f(s);
        dstb[lane + q4 * 64] = s;
      }
    } else {
      const bool isq = hr < 8;
      const int cb = isq ? hr * 256 : 2048 + (hr - 8) * 256;
      float v0 = bf2f(row[cb + lane]);
      float v1 = bf2f(row[cb + lane + 64]);
      float v2 = bf2f(row[cb + lane + 128]);
      float v3 = bf2f(row[cb + lane + 192]);
      float ss = v0 * v0 + v1 * v1 + v2 * v2 + v3 * v3;
      #pragma unroll
      for (int off = 1; off < 64; off <<= 1) ss += __shfl_xor(ss, off);
      float sc = rsqrtf(ss * (1.0f / 256.0f) + 1e-6f);
      if (isq) sc *= 0.0625f;  // QUERY_PRE_ATTN_SCALAR^-0.5
      const float* wn = isq ? qnw : knw;
      v0 *= sc * wn[lane];
      v1 *= sc * wn[lane + 64];
      v2 *= sc * wn[lane + 128];
      v3 *= sc * wn[lane + 192];
      const float n0 = v0 * c0 - v2 * s0;
      const float n2 = v2 * c0 + v0 * s0;
      const float n1 = v1 * c1 - v3 * s1;
      const float n3 = v3 * c1 + v1 * s1;
      if (isq) {
        u16* dst = qb + (size_t)t * 2048 + hr * 256;
        dst[lane]       = f2bf(n0);
        dst[lane + 64]  = f2bf(n1);
        dst[lane + 128] = f2bf(n2);
        dst[lane + 192] = f2bf(n3);
      } else {
        const int kk = hr - 8;
        float* dstf = kvout + ((size_t)t * NKV + kk) * HD;
        dstf[lane]       = n0;
        dstf[lane + 64]  = n1;
        dstf[lane + 128] = n2;
        dstf[lane + 192] = n3;
        u16* dstb = kb + ((size_t)t * NKV + kk) * HD;
        dstb[lane]       = f2bf(n0);
        dstb[lane + 64]  = f2bf(n1);
        dstb[lane + 128] = f2bf(n2);
        dstb[lane + 192] = f2bf(n3);
      }
    }
  }
}

// ---------------------------------------------------------------------------
// Per-head V transpose: vb (T x NKV x HD bf16) -> vt (NKV x HD x T bf16)
__global__ __launch_bounds__(256) void transpose_v(
    const u16* __restrict__ vc, u16* __restrict__ vt)
{
  __shared__ u16 tile[64][65];
  const int kk = blockIdx.z;
  const int t0 = blockIdx.y * 64, h0 = blockIdx.x * 64;
  const int tr = threadIdx.x >> 6, tc = threadIdx.x & 63;
  #pragma unroll
  for (int i = 0; i < 16; ++i) {
    int tt = tr + i * 4;
    tile[tt][tc] = vc[((size_t)(t0 + tt) * NKV + kk) * HD + h0 + tc];
  }
  __syncthreads();
  #pragma unroll
  for (int i = 0; i < 16; ++i) {
    int h = tr + i * 4;
    vt[(size_t)kk * HD * T_TOK + (size_t)(h0 + h) * T_TOK + t0 + tc] = tile[tc][h];
  }
}

// ---------------------------------------------------------------------------
// Flash attention v3: wave-local softmax. Each wave owns 16 q-rows x all keys.
// No cross-wave softmax state, 2 barriers/tile, async K/V prefetch (T14).
// K/V LDS XOR-swizzled; P in per-wave private LDS slice (no barrier needed).
__global__ __launch_bounds__(256, 2) void attn_kernel(
    const u16* __restrict__ qb, const u16* __restrict__ kc,
    const u16* __restrict__ vt, u16* __restrict__ ob)
{
  __shared__ __align__(16) u16 Ks[64 * 256];    // [key][d] swz, 32KB
  __shared__ __align__(16) u16 Vts[256 * 64];   // [d][key] swz, 32KB
  __shared__ __align__(16) u16 Ps[4][16 * 64];  // per-wave [qrow][key] swz, 8KB

  const int n = blockIdx.y, kk = n >> 1;
  const int t0 = blockIdx.x * 64;
  const int tid = threadIdx.x;
  const int wave = tid >> 6, lane = tid & 63;
  const int lg = lane >> 4, lc = lane & 15;
  const int lswz = (lc & 7) << 4;
  const f32x4 zf = {0.f, 0.f, 0.f, 0.f};

  // Q fragments straight from global (rows t0+wave*16+lc)
  bf16x8 qf[8];
  {
    const u16* qp = qb + (size_t)(t0 + wave * 16 + lc) * 2048 + n * 256 + lg * 8;
    #pragma unroll
    for (int ks = 0; ks < 8; ++ks) qf[ks] = *(const bf16x8*)(qp + ks * 32);
  }

  f32x4 o_acc[16];
  #pragma unroll
  for (int j = 0; j < 16; ++j) o_acc[j] = zf;
  float m_r[4], l_r[4];
  #pragma unroll
  for (int r = 0; r < 4; ++r) { m_r[r] = -1e30f; l_r[r] = 0.f; }

  const int mtile = t0 >> 6;
  const int ktf = (mtile >= 16) ? (mtile - 16) : 0;

  // staging mapping
  const int krow = tid >> 5;           // + is*8 (K rows = keys)
  const int kcol = (tid & 31) * 8;     // elems of d
  const int kswz = (krow & 7) << 4;
  const int vrow = tid >> 3;           // + is*32 (V^T rows = d)
  const int vcol = (tid & 7) * 8;      // elems of key
  const int vswz = (vrow & 7) << 4;

  // prologue: first tile into regs
  bf16x8 rk[8], rv[8];
  {
    const int kb = ktf * 64;
    const u16* kp = kc + (size_t)(kb + krow) * (NKV * HD) + kk * HD + kcol;
    const u16* vp = vt + (size_t)kk * (HD * T_TOK) + (size_t)vrow * T_TOK + kb + vcol;
    #pragma unroll
    for (int is = 0; is < 8; ++is) rk[is] = *(const bf16x8*)(kp + (size_t)(is * 8) * (NKV * HD));
    #pragma unroll
    for (int is = 0; is < 8; ++is) rv[is] = *(const bf16x8*)(vp + (size_t)(is * 32) * T_TOK);
  }

  for (int kt = ktf; kt <= mtile; ++kt) {
    const int kb = kt * 64;
    // write staged regs -> LDS (swizzled)
    #pragma unroll
    for (int is = 0; is < 8; ++is)
      *(bf16x8*)((char*)Ks + (((krow + is * 8) * 512 + kcol * 2) ^ kswz)) = rk[is];
    #pragma unroll
    for (int is = 0; is < 8; ++is)
      *(bf16x8*)((char*)Vts + (((vrow + is * 32) * 128 + vcol * 2) ^ vswz)) = rv[is];
    __syncthreads();

    // prefetch next tile (hides HBM latency under compute)
    if (kt < mtile) {
      const int nb = kb + 64;
      const u16* kp = kc + (size_t)(nb + krow) * (NKV * HD) + kk * HD + kcol;
      const u16* vp = vt + (size_t)kk * (HD * T_TOK) + (size_t)vrow * T_TOK + nb + vcol;
      #pragma unroll
      for (int is = 0; is < 8; ++is) rk[is] = *(const bf16x8*)(kp + (size_t)(is * 8) * (NKV * HD));
      #pragma unroll
      for (int is = 0; is < 8; ++is) rv[is] = *(const bf16x8*)(vp + (size_t)(is * 32) * T_TOK);
    }

    // ---- S = Q K^T : this wave's 16 rows x 64 keys
    f32x4 sf[4];
    #pragma unroll
    for (int j = 0; j < 4; ++j) sf[j] = zf;
    __builtin_amdgcn_s_setprio(1);
    #pragma unroll
    for (int ks = 0; ks < 8; ++ks)
      #pragma unroll
      for (int j = 0; j < 4; ++j) {
        const int row = j * 16 + lc;
        bf16x8 kf = *(const bf16x8*)((char*)Ks + ((row * 512 + ks * 64 + lg * 16) ^ lswz));
        sf[j] = __builtin_amdgcn_mfma_f32_16x16x32_bf16(qf[ks], kf, sf[j], 0, 0, 0);
      }
    __builtin_amdgcn_s_setprio(0);

    // ---- mask (skip fully-interior tiles)
    const bool interior = (kb >= t0 - 960) && (kb <= t0 - 64);
    if (!interior) {
      #pragma unroll
      for (int j = 0; j < 4; ++j) {
        const int gcol = kb + j * 16 + lc;
        #pragma unroll
        for (int r = 0; r < 4; ++r) {
          const int grow = t0 + wave * 16 + lg * 4 + r;
          if ((unsigned)(grow - gcol) >= WIN) sf[j][r] = -1e30f;
        }
      }
    }

    // ---- wave-local online softmax (rows lg*4+r, reduce over 16 lc lanes)
    float a_r[4];
    #pragma unroll
    for (int r = 0; r < 4; ++r) {
      float v = fmaxf(fmaxf(sf[0][r], sf[1][r]), fmaxf(sf[2][r], sf[3][r]));
      v = fmaxf(v, __shfl_xor(v, 1));
      v = fmaxf(v, __shfl_xor(v, 2));
      v = fmaxf(v, __shfl_xor(v, 4));
      v = fmaxf(v, __shfl_xor(v, 8));
      const float mn = fmaxf(m_r[r], v);
      a_r[r] = __expf(m_r[r] - mn);
      m_r[r] = mn;
    }

    // ---- P = exp(S-m) -> own LDS slice; row sums; l update
    char* myP = (char*)&Ps[wave][0];
    #pragma unroll
    for (int r = 0; r < 4; ++r) {
      const int row = lg * 4 + r;
      const int rsw = (row & 7) << 4;
      float su = 0.f;
      #pragma unroll
      for (int j = 0; j < 4; ++j) {
        const float p = __expf(sf[j][r] - m_r[r]);
        su += p;
        *(u16*)(myP + ((row * 128 + (j * 16 + lc) * 2) ^ rsw)) = f2bf(p);
      }
      su += __shfl_xor(su, 1);
      su += __shfl_xor(su, 2);
      su += __shfl_xor(su, 4);
      su += __shfl_xor(su, 8);
      l_r[r] = l_r[r] * a_r[r] + su;
    }

    // ---- rescale O
    #pragma unroll
    for (int j = 0; j < 16; ++j) {
      o_acc[j][0] *= a_r[0];
      o_acc[j][1] *= a_r[1];
      o_acc[j][2] *= a_r[2];
      o_acc[j][3] *= a_r[3];
    }

    // ---- O += P * V (P read is wave-private: lgkmcnt only, no barrier)
    bf16x8 pa[2];
    #pragma unroll
    for (int ks = 0; ks < 2; ++ks)
      pa[ks] = *(const bf16x8*)(myP + ((lc * 128 + ks * 64 + lg * 16) ^ lswz));
    __builtin_amdgcn_s_setprio(1);
    #pragma unroll
    for (int ks = 0; ks < 2; ++ks)
      #pragma unroll
      for (int j = 0; j < 16; ++j) {
        const int row = j * 16 + lc;
        bf16x8 vf = *(const bf16x8*)((char*)Vts + ((row * 128 + ks * 64 + lg * 16) ^ lswz));
        o_acc[j] = __builtin_amdgcn_mfma_f32_16x16x32_bf16(pa[ks], vf, o_acc[j], 0, 0, 0);
      }
    __builtin_amdgcn_s_setprio(0);
    __syncthreads();  // all waves done reading Ks/Vts before next staging
  }

  // ---- epilogue: O / l -> attn buffer (T x 2048 bf16)
  #pragma unroll
  for (int r = 0; r < 4; ++r) {
    const float li = 1.f / l_r[r];
    const size_t rowb = (size_t)(t0 + wave * 16 + lg * 4 + r) * 2048 + n * 256 + lc;
    #pragma unroll
    for (int j = 0; j < 16; ++j)
      ob[rowb + j * 16] = f2bf(o_acc[j][r] * li);
  }
}

// ---------------------------------------------------------------------------
extern "C" void kernel_launch(void* const* d_in, const int* in_sizes, int n_in,
                              void* d_out, int out_size, void* d_ws, size_t ws_size,
                              hipStream_t stream)
{
  (void)in_sizes; (void)n_in; (void)out_size; (void)ws_size;
  const float* x   = (const float*)d_in[0];
  const float* wq  = (const float*)d_in[1];
  const float* wk  = (const float*)d_in[2];
  const float* wv  = (const float*)d_in[3];
  const float* wo  = (const float*)d_in[4];
  const float* qnw = (const float*)d_in[5];
  const float* knw = (const float*)d_in[6];
  const int*   pos = (const int*)d_in[7];
  float* out = (float*)d_out;  // f32: [2*T*NKV*HD kv cache][T*DM o]

  // workspace layout (peak 86 MB), lifetime-aliased
  char* ws = (char*)d_ws;
  u16* woT   = (u16*)(ws);                    // 2560x2048 bf16 (10.5 MB), live to end
  u16* xb    = (u16*)(ws + 10485760);         // T x DM bf16 (21.0 MB)
  u16* wqkvT = (u16*)(ws + 31457280);         // 4096 x DM bf16 (21.0 MB)
  u16* qkv   = (u16*)(ws + 52428800);         // T x 4096 bf16 (33.6 MB)
  u16* q_b   = xb;                            // alias: xb dead after gemm1 (16.8 MB)
  u16* kb    = wqkvT;                         // alias: wqkvT dead after gemm1 (8.4 MB)
  u16* vb    = (u16*)(ws + 31457280 + 8388608); // (8.4 MB, still inside wqkvT)
  u16* vtb   = qkv;                           // alias: qkv dead after fuse (8.4 MB)
  u16* attn  = (u16*)(ws + 52428800 + 8388608); // (16.8 MB, inside qkv region)

  convert_f32_bf16<<<2048, 256, 0, stream>>>(x, xb, T_TOK * DM);
  transpose_f32_bf16<<<dim3(32, 40), 256, 0, stream>>>(wq, wqkvT, DM, 2048);
  transpose_f32_bf16<<<dim3(16, 40), 256, 0, stream>>>(wk, wqkvT + 2048 * DM, DM, 1024);
  transpose_f32_bf16<<<dim3(16, 40), 256, 0, stream>>>(wv, wqkvT + 3072 * DM, DM, 1024);
  transpose_f32_bf16<<<dim3(40, 32), 256, 0, stream>>>(wo, woT, 2048, DM);

  // QKV projection: (T x DM) * (DM x 4096) -> T x 4096 bf16 (256 blocks, XCD-swz)
  gemm256<false><<<256, 512, 0, stream>>>(xb, wqkvT, qkv, DM, DM, DM, 4096);

  // RMSNorm + scale + RoPE; k/v f32 into kv cache (d_out) + bf16 copies
  fuse_norm_rope<<<T_TOK, 256, 0, stream>>>(qkv, qnw, knw, pos, q_b, kb, vb, out);

  // V^T per head for PV MFMA B-operand
  transpose_v<<<dim3(4, 64, 4), 256, 0, stream>>>(vb, vtb);

  // flash attention -> attn (T x 2048 bf16)
  attn_kernel<<<dim3(64, 8), 256, 0, stream>>>(q_b, kb, vtb, attn);

  // output projection: (T x 2048) * (2048 x DM) -> o (f32) in d_out (160 blocks)
  gemm256<true><<<160, 512, 0, stream>>>(attn, woT, out + 2 * (size_t)T_TOK * NKV * HD,
                                         2048, 2048, 2048, DM);
}

// Round 9
// 269.841 us; speedup vs baseline: 1.7128x; 1.7128x over previous
//
#include <hip/hip_runtime.h>
#include <stdint.h>

// Problem constants (Gemma3 attention block)
#define T_TOK 4096
#define DM    2560
#define NQ    8
#define NKV   4
#define HD    256
#define WIN   1024

using bf16x8 = __attribute__((ext_vector_type(8))) short;
using f32x4  = __attribute__((ext_vector_type(4))) float;
typedef unsigned short u16;

__device__ __forceinline__ u16 f2bf(float x) {
  union { float f; uint32_t u; } v; v.f = x;
  uint32_t u = v.u;
  return (u16)((u + 0x7fffu + ((u >> 16) & 1u)) >> 16);  // RNE
}
__device__ __forceinline__ float bf2f(u16 b) {
  union { uint32_t u; float f; } v; v.u = ((uint32_t)b) << 16;
  return v.f;
}

// async global->LDS, 16B per lane. LDS dest is wave-uniform base; HW adds lane*16.
__device__ __forceinline__ void async_cp16(const void* g, void* lds) {
  __builtin_amdgcn_global_load_lds(
      (const __attribute__((address_space(1))) uint32_t*)(uintptr_t)g,
      (__attribute__((address_space(3))) uint32_t*)(uint32_t)(uintptr_t)lds,
      16, 0, 0);
}

// ---------------------------------------------------------------------------
// f32 -> bf16 elementwise convert (vectorized float4 loads)
__global__ __launch_bounds__(256) void convert_f32_bf16(
    const float* __restrict__ in, u16* __restrict__ out, int n)
{
  for (int i = (blockIdx.x * 256 + threadIdx.x) * 4; i < n; i += gridDim.x * 256 * 4) {
    float4 v = *(const float4*)(in + i);
    ushort4 o;
    o.x = f2bf(v.x); o.y = f2bf(v.y); o.z = f2bf(v.z); o.w = f2bf(v.w);
    *(ushort4*)(out + i) = o;
  }
}

// ---------------------------------------------------------------------------
// Tiled transpose + convert: in f32 (R x C) row-major -> out bf16 (C x R)
__global__ __launch_bounds__(256) void transpose_f32_bf16(
    const float* __restrict__ in, u16* __restrict__ out, int R, int C)
{
  __shared__ u16 tile[64][65];
  const int r0 = blockIdx.y * 64, c0 = blockIdx.x * 64;
  const int tr = threadIdx.x >> 6, tc = threadIdx.x & 63;
  #pragma unroll
  for (int i = 0; i < 16; ++i) {
    int r = tr + i * 4;
    tile[r][tc] = f2bf(in[(size_t)(r0 + r) * C + c0 + tc]);
  }
  __syncthreads();
  #pragma unroll
  for (int i = 0; i < 16; ++i) {
    int c = tr + i * 4;
    out[(size_t)(c0 + c) * R + r0 + tc] = tile[tc][c];
  }
}

// ---------------------------------------------------------------------------
// 256x256 bf16 GEMM, counted-vmcnt double-buffered pipeline.
// C(MxN) = A(MxK,row-major,lda) * B^T, B is (N x K,row-major,ldb).
// 8 waves (2Mx4N), BK=64, LDS 128 KiB. 1D grid, XCD-aware swizzle (GY=16).
template<bool F32OUT>
__global__ __launch_bounds__(512, 2) void gemm256(
    const u16* __restrict__ A, const u16* __restrict__ B, void* __restrict__ Cv,
    int Kd, int lda, int ldb, int ldc)
{
  __shared__ __align__(16) u16 lds[2][2][256 * 64];  // [buf][A|B] 128 KiB
  const int tid = threadIdx.x;
  const int wave = tid >> 6, lane = tid & 63;
  const int lg = lane >> 4, lc = lane & 15;
  const int wr = wave >> 2, wc = wave & 3;  // 2 x 4 wave grid
  // XCD swizzle: consecutive remapped ids cluster on one XCD, column-major
  const int nwg = gridDim.x, bid = blockIdx.x;
  const int nid = (bid & 7) * (nwg >> 3) + (bid >> 3);
  const int m0 = (nid & 15) * 256, n0 = (nid >> 4) * 256;
  const int NT = Kd >> 6;

  const int srow = tid >> 3;
  const int scol = ((tid & 7) * 16) ^ ((srow & 7) << 4);  // pre-swizzled source col
  const u16* Ag = A + (size_t)(m0 + srow) * lda + (scol >> 1);
  const u16* Bg = B + (size_t)(n0 + srow) * ldb + (scol >> 1);
  char* ldsA0 = (char*)&lds[0][0][0];
  char* ldsB0 = (char*)&lds[0][1][0];
  char* ldsA1 = (char*)&lds[1][0][0];
  char* ldsB1 = (char*)&lds[1][1][0];

  #define STAGE256(LA, LB, KT) do {                                         \
    const int kc_ = (KT) * 64;                                              \
    _Pragma("unroll")                                                       \
    for (int li = 0; li < 4; ++li)                                          \
      async_cp16(Ag + (size_t)(li * 64) * lda + kc_, (LA) + li * 8192 + wave * 1024); \
    _Pragma("unroll")                                                       \
    for (int li = 0; li < 4; ++li)                                          \
      async_cp16(Bg + (size_t)(li * 64) * ldb + kc_, (LB) + li * 8192 + wave * 1024); \
  } while (0)

  const f32x4 zf = {0.f, 0.f, 0.f, 0.f};
  f32x4 acc[8][4];
  #pragma unroll
  for (int i = 0; i < 8; ++i)
    #pragma unroll
    for (int j = 0; j < 4; ++j) acc[i][j] = zf;

  STAGE256(ldsA0, ldsB0, 0);
  STAGE256(ldsA1, ldsB1, 1);
  asm volatile("s_waitcnt vmcnt(8)" ::: "memory");
  __builtin_amdgcn_s_barrier();
  __builtin_amdgcn_sched_barrier(0);

  for (int t = 0; t < NT; ++t) {
    const int cur = t & 1;
    const u16* Ab = &lds[cur][0][0];
    const u16* Bb = &lds[cur][1][0];

    bf16x8 bf[4][2];
    #pragma unroll
    for (int j = 0; j < 4; ++j)
      #pragma unroll
      for (int k2 = 0; k2 < 2; ++k2) {
        const int row = wc * 64 + j * 16 + lc;
        const int cb = k2 * 64 + lg * 16;
        bf[j][k2] = *(const bf16x8*)((const char*)Bb + row * 128 + (cb ^ ((row & 7) << 4)));
      }

    #pragma unroll
    for (int p = 0; p < 4; ++p) {
      bf16x8 af[2][2];
      #pragma unroll
      for (int im = 0; im < 2; ++im)
        #pragma unroll
        for (int k2 = 0; k2 < 2; ++k2) {
          const int row = wr * 128 + (p * 2 + im) * 16 + lc;
          const int cb = k2 * 64 + lg * 16;
          af[im][k2] = *(const bf16x8*)((const char*)Ab + row * 128 + (cb ^ ((row & 7) << 4)));
        }
      __builtin_amdgcn_s_setprio(1);
      #pragma unroll
      for (int im = 0; im < 2; ++im)
        #pragma unroll
        for (int j = 0; j < 4; ++j)
          #pragma unroll
          for (int k2 = 0; k2 < 2; ++k2)
            acc[p * 2 + im][j] = __builtin_amdgcn_mfma_f32_16x16x32_bf16(
                af[im][k2], bf[j][k2], acc[p * 2 + im][j], 0, 0, 0);
      __builtin_amdgcn_s_setprio(0);
    }

    __builtin_amdgcn_s_barrier();
    __builtin_amdgcn_sched_barrier(0);
    int nk = t + 2; if (nk > NT - 1) nk = NT - 1;
    if (cur == 0) { STAGE256(ldsA0, ldsB0, nk); } else { STAGE256(ldsA1, ldsB1, nk); }
    asm volatile("s_waitcnt vmcnt(8)" ::: "memory");
    __builtin_amdgcn_s_barrier();
    __builtin_amdgcn_sched_barrier(0);
  }
  #undef STAGE256

  #pragma unroll
  for (int i = 0; i < 8; ++i)
    #pragma unroll
    for (int j = 0; j < 4; ++j)
      #pragma unroll
      for (int r = 0; r < 4; ++r) {
        const int row = m0 + wr * 128 + i * 16 + lg * 4 + r;
        const int col = n0 + wc * 64 + j * 16 + lc;
        if (F32OUT) ((float*)Cv)[(size_t)row * ldc + col] = acc[i][j][r];
        else        ((u16*)Cv)[(size_t)row * ldc + col] = f2bf(acc[i][j][r]);
      }
}

// ---------------------------------------------------------------------------
// Fused RMSNorm + query-scale + RoPE. Reads qkv (T x 4096 bf16):
// cols [0,2048) = q (n-major), [2048,3072) = k, [3072,4096) = v.
__global__ __launch_bounds__(256) void fuse_norm_rope(
    const u16* __restrict__ qkv, const float* __restrict__ qnw, const float* __restrict__ knw,
    const int* __restrict__ pos, u16* __restrict__ qb, u16* __restrict__ kb,
    u16* __restrict__ vb, float* __restrict__ kvout)
{
  const int t = blockIdx.x;
  const int wave = threadIdx.x >> 6, lane = threadIdx.x & 63;
  const float p = (float)pos[t];
  const float kf = 0.10381025296523007f;  // log2(10000)/128
  float s0, c0, s1, c1;
  sincosf(p * exp2f(-(float)lane * kf), &s0, &c0);
  sincosf(p * exp2f(-(float)(lane + 64) * kf), &s1, &c1);
  const u16* row = qkv + (size_t)t * 4096;

  for (int pp = 0; pp < 4; ++pp) {
    const int hr = pp * 4 + wave;  // 0..7 q, 8..11 k, 12..15 v
    if (hr >= 12) {
      const int kk = hr - 12;
      const u16* src = row + 3072 + kk * 256;
      float* dstf = kvout + (size_t)T_TOK * NKV * HD + ((size_t)t * NKV + kk) * HD;
      u16*   dstb = vb + ((size_t)t * NKV + kk) * HD;
      #pragma unroll
      for (int q4 = 0; q4 < 4; ++q4) {
        const u16 s = src[lane + q4 * 64];
        dstf[lane + q4 * 64] = bf2f(s);
        dstb[lane + q4 * 64] = s;
      }
    } else {
      const bool isq = hr < 8;
      const int cb = isq ? hr * 256 : 2048 + (hr - 8) * 256;
      float v0 = bf2f(row[cb + lane]);
      float v1 = bf2f(row[cb + lane + 64]);
      float v2 = bf2f(row[cb + lane + 128]);
      float v3 = bf2f(row[cb + lane + 192]);
      float ss = v0 * v0 + v1 * v1 + v2 * v2 + v3 * v3;
      #pragma unroll
      for (int off = 1; off < 64; off <<= 1) ss += __shfl_xor(ss, off);
      float sc = rsqrtf(ss * (1.0f / 256.0f) + 1e-6f);
      if (isq) sc *= 0.0625f;  // QUERY_PRE_ATTN_SCALAR^-0.5
      const float* wn = isq ? qnw : knw;
      v0 *= sc * wn[lane];
      v1 *= sc * wn[lane + 64];
      v2 *= sc * wn[lane + 128];
      v3 *= sc * wn[lane + 192];
      const float n0 = v0 * c0 - v2 * s0;
      const float n2 = v2 * c0 + v0 * s0;
      const float n1 = v1 * c1 - v3 * s1;
      const float n3 = v3 * c1 + v1 * s1;
      if (isq) {
        u16* dst = qb + (size_t)t * 2048 + hr * 256;
        dst[lane]       = f2bf(n0);
        dst[lane + 64]  = f2bf(n1);
        dst[lane + 128] = f2bf(n2);
        dst[lane + 192] = f2bf(n3);
      } else {
        const int kk = hr - 8;
        float* dstf = kvout + ((size_t)t * NKV + kk) * HD;
        dstf[lane]       = n0;
        dstf[lane + 64]  = n1;
        dstf[lane + 128] = n2;
        dstf[lane + 192] = n3;
        u16* dstb = kb + ((size_t)t * NKV + kk) * HD;
        dstb[lane]       = f2bf(n0);
        dstb[lane + 64]  = f2bf(n1);
        dstb[lane + 128] = f2bf(n2);
        dstb[lane + 192] = f2bf(n3);
      }
    }
  }
}

// ---------------------------------------------------------------------------
// Per-head V transpose: vb (T x NKV x HD bf16) -> vt (NKV x HD x T bf16)
__global__ __launch_bounds__(256) void transpose_v(
    const u16* __restrict__ vc, u16* __restrict__ vt)
{
  __shared__ u16 tile[64][65];
  const int kk = blockIdx.z;
  const int t0 = blockIdx.y * 64, h0 = blockIdx.x * 64;
  const int tr = threadIdx.x >> 6, tc = threadIdx.x & 63;
  #pragma unroll
  for (int i = 0; i < 16; ++i) {
    int tt = tr + i * 4;
    tile[tt][tc] = vc[((size_t)(t0 + tt) * NKV + kk) * HD + h0 + tc];
  }
  __syncthreads();
  #pragma unroll
  for (int i = 0; i < 16; ++i) {
    int h = tr + i * 4;
    vt[(size_t)kk * HD * T_TOK + (size_t)(h0 + h) * T_TOK + t0 + tc] = tile[tc][h];
  }
}

// ---------------------------------------------------------------------------
// Flash attention v4: wave-local softmax (from v3) + global_load_lds staging
// with pre-swizzled per-lane source addresses (no staging registers -> no
// spill). Single K/V buffer, 2 barriers/tile, per-wave private P slice.
__global__ __launch_bounds__(256, 2) void attn_kernel(
    const u16* __restrict__ qb, const u16* __restrict__ kc,
    const u16* __restrict__ vt, u16* __restrict__ ob)
{
  __shared__ __align__(16) u16 Ks[64 * 256];    // [key][d] swz, 32KB
  __shared__ __align__(16) u16 Vts[256 * 64];   // [d][key] swz, 32KB
  __shared__ __align__(16) u16 Ps[4][16 * 64];  // per-wave [qrow][key] swz, 8KB

  const int n = blockIdx.y, kk = n >> 1;
  const int t0 = blockIdx.x * 64;
  const int tid = threadIdx.x;
  const int wave = tid >> 6, lane = tid & 63;
  const int lg = lane >> 4, lc = lane & 15;
  const int lswz = (lc & 7) << 4;
  const f32x4 zf = {0.f, 0.f, 0.f, 0.f};

  // staging geometry (global_load_lds: linear LDS dest, pre-swizzled source)
  // K: rows of 512B (256 d-elems); per issue 256 threads cover 8 rows.
  const int lrowK = wave * 2 + (lane >> 5);                   // LDS row in issue group
  const int scolK = ((lane & 31) * 16) ^ ((lrowK & 7) << 4);  // swizzled src byte-col
  // V^T: rows of 128B (64 key-elems); per issue 256 threads cover 32 rows.
  const int lrowV = wave * 8 + (lane >> 3);
  const int scolV = ((lane & 7) * 16) ^ ((lrowV & 7) << 4);

  // Q fragments straight from global (rows t0+wave*16+lc)
  bf16x8 qf[8];
  {
    const u16* qp = qb + (size_t)(t0 + wave * 16 + lc) * 2048 + n * 256 + lg * 8;
    #pragma unroll
    for (int ks = 0; ks < 8; ++ks) qf[ks] = *(const bf16x8*)(qp + ks * 32);
  }

  f32x4 o_acc[16];
  #pragma unroll
  for (int j = 0; j < 16; ++j) o_acc[j] = zf;
  float m_r[4], l_r[4];
  #pragma unroll
  for (int r = 0; r < 4; ++r) { m_r[r] = -1e30f; l_r[r] = 0.f; }

  const int mtile = t0 >> 6;
  const int ktf = (mtile >= 16) ? (mtile - 16) : 0;

  for (int kt = ktf; kt <= mtile; ++kt) {
    const int kb = kt * 64;
    // ---- stage K (8 issues) + V^T (8 issues) via global_load_lds
    {
      const u16* kp = kc + (size_t)(kb + lrowK) * (NKV * HD) + kk * HD + (scolK >> 1);
      #pragma unroll
      for (int is = 0; is < 8; ++is)
        async_cp16(kp + (size_t)(is * 8) * (NKV * HD), (char*)Ks + is * 4096 + wave * 1024);
      const u16* vp = vt + (size_t)kk * (HD * T_TOK) + (size_t)lrowV * T_TOK + kb + (scolV >> 1);
      #pragma unroll
      for (int is = 0; is < 8; ++is)
        async_cp16(vp + (size_t)(is * 32) * T_TOK, (char*)Vts + is * 4096 + wave * 1024);
    }
    __syncthreads();  // drains vmcnt(0): staged data visible to all waves

    // ---- S = Q K^T : this wave's 16 rows x 64 keys
    f32x4 sf[4];
    #pragma unroll
    for (int j = 0; j < 4; ++j) sf[j] = zf;
    __builtin_amdgcn_s_setprio(1);
    #pragma unroll
    for (int ks = 0; ks < 8; ++ks)
      #pragma unroll
      for (int j = 0; j < 4; ++j) {
        const int row = j * 16 + lc;
        bf16x8 kf = *(const bf16x8*)((char*)Ks + ((row * 512 + ks * 64 + lg * 16) ^ lswz));
        sf[j] = __builtin_amdgcn_mfma_f32_16x16x32_bf16(qf[ks], kf, sf[j], 0, 0, 0);
      }
    __builtin_amdgcn_s_setprio(0);

    // ---- mask (skip fully-interior tiles)
    const bool interior = (kb >= t0 - 960) && (kb <= t0 - 64);
    if (!interior) {
      #pragma unroll
      for (int j = 0; j < 4; ++j) {
        const int gcol = kb + j * 16 + lc;
        #pragma unroll
        for (int r = 0; r < 4; ++r) {
          const int grow = t0 + wave * 16 + lg * 4 + r;
          if ((unsigned)(grow - gcol) >= WIN) sf[j][r] = -1e30f;
        }
      }
    }

    // ---- wave-local online softmax (rows lg*4+r, reduce over 16 lc lanes)
    float a_r[4];
    #pragma unroll
    for (int r = 0; r < 4; ++r) {
      float v = fmaxf(fmaxf(sf[0][r], sf[1][r]), fmaxf(sf[2][r], sf[3][r]));
      v = fmaxf(v, __shfl_xor(v, 1));
      v = fmaxf(v, __shfl_xor(v, 2));
      v = fmaxf(v, __shfl_xor(v, 4));
      v = fmaxf(v, __shfl_xor(v, 8));
      const float mn = fmaxf(m_r[r], v);
      a_r[r] = __expf(m_r[r] - mn);
      m_r[r] = mn;
    }

    // ---- P = exp(S-m) -> own LDS slice; row sums; l update
    char* myP = (char*)&Ps[wave][0];
    #pragma unroll
    for (int r = 0; r < 4; ++r) {
      const int row = lg * 4 + r;
      const int rsw = (row & 7) << 4;
      float su = 0.f;
      #pragma unroll
      for (int j = 0; j < 4; ++j) {
        const float p = __expf(sf[j][r] - m_r[r]);
        su += p;
        *(u16*)(myP + ((row * 128 + (j * 16 + lc) * 2) ^ rsw)) = f2bf(p);
      }
      su += __shfl_xor(su, 1);
      su += __shfl_xor(su, 2);
      su += __shfl_xor(su, 4);
      su += __shfl_xor(su, 8);
      l_r[r] = l_r[r] * a_r[r] + su;
    }

    // ---- rescale O
    #pragma unroll
    for (int j = 0; j < 16; ++j) {
      o_acc[j][0] *= a_r[0];
      o_acc[j][1] *= a_r[1];
      o_acc[j][2] *= a_r[2];
      o_acc[j][3] *= a_r[3];
    }

    // ---- O += P * V (P read is wave-private: lgkmcnt only, no barrier)
    bf16x8 pa[2];
    #pragma unroll
    for (int ks = 0; ks < 2; ++ks)
      pa[ks] = *(const bf16x8*)(myP + ((lc * 128 + ks * 64 + lg * 16) ^ lswz));
    __builtin_amdgcn_s_setprio(1);
    #pragma unroll
    for (int ks = 0; ks < 2; ++ks)
      #pragma unroll
      for (int j = 0; j < 16; ++j) {
        const int row = j * 16 + lc;
        bf16x8 vf = *(const bf16x8*)((char*)Vts + ((row * 128 + ks * 64 + lg * 16) ^ lswz));
        o_acc[j] = __builtin_amdgcn_mfma_f32_16x16x32_bf16(pa[ks], vf, o_acc[j], 0, 0, 0);
      }
    __builtin_amdgcn_s_setprio(0);
    __syncthreads();  // all waves done reading Ks/Vts before next staging
  }

  // ---- epilogue: O / l -> attn buffer (T x 2048 bf16)
  #pragma unroll
  for (int r = 0; r < 4; ++r) {
    const float li = 1.f / l_r[r];
    const size_t rowb = (size_t)(t0 + wave * 16 + lg * 4 + r) * 2048 + n * 256 + lc;
    #pragma unroll
    for (int j = 0; j < 16; ++j)
      ob[rowb + j * 16] = f2bf(o_acc[j][r] * li);
  }
}

// ---------------------------------------------------------------------------
extern "C" void kernel_launch(void* const* d_in, const int* in_sizes, int n_in,
                              void* d_out, int out_size, void* d_ws, size_t ws_size,
                              hipStream_t stream)
{
  (void)in_sizes; (void)n_in; (void)out_size; (void)ws_size;
  const float* x   = (const float*)d_in[0];
  const float* wq  = (const float*)d_in[1];
  const float* wk  = (const float*)d_in[2];
  const float* wv  = (const float*)d_in[3];
  const float* wo  = (const float*)d_in[4];
  const float* qnw = (const float*)d_in[5];
  const float* knw = (const float*)d_in[6];
  const int*   pos = (const int*)d_in[7];
  float* out = (float*)d_out;  // f32: [2*T*NKV*HD kv cache][T*DM o]

  // workspace layout (peak 86 MB), lifetime-aliased
  char* ws = (char*)d_ws;
  u16* woT   = (u16*)(ws);                    // 2560x2048 bf16 (10.5 MB), live to end
  u16* xb    = (u16*)(ws + 10485760);         // T x DM bf16 (21.0 MB)
  u16* wqkvT = (u16*)(ws + 31457280);         // 4096 x DM bf16 (21.0 MB)
  u16* qkv   = (u16*)(ws + 52428800);         // T x 4096 bf16 (33.6 MB)
  u16* q_b   = xb;                            // alias: xb dead after gemm1 (16.8 MB)
  u16* kb    = wqkvT;                         // alias: wqkvT dead after gemm1 (8.4 MB)
  u16* vb    = (u16*)(ws + 31457280 + 8388608); // (8.4 MB, still inside wqkvT)
  u16* vtb   = qkv;                           // alias: qkv dead after fuse (8.4 MB)
  u16* attn  = (u16*)(ws + 52428800 + 8388608); // (16.8 MB, inside qkv region)

  convert_f32_bf16<<<2048, 256, 0, stream>>>(x, xb, T_TOK * DM);
  transpose_f32_bf16<<<dim3(32, 40), 256, 0, stream>>>(wq, wqkvT, DM, 2048);
  transpose_f32_bf16<<<dim3(16, 40), 256, 0, stream>>>(wk, wqkvT + 2048 * DM, DM, 1024);
  transpose_f32_bf16<<<dim3(16, 40), 256, 0, stream>>>(wv, wqkvT + 3072 * DM, DM, 1024);
  transpose_f32_bf16<<<dim3(40, 32), 256, 0, stream>>>(wo, woT, 2048, DM);

  // QKV projection: (T x DM) * (DM x 4096) -> T x 4096 bf16 (256 blocks, XCD-swz)
  gemm256<false><<<256, 512, 0, stream>>>(xb, wqkvT, qkv, DM, DM, DM, 4096);

  // RMSNorm + scale + RoPE; k/v f32 into kv cache (d_out) + bf16 copies
  fuse_norm_rope<<<T_TOK, 256, 0, stream>>>(qkv, qnw, knw, pos, q_b, kb, vb, out);

  // V^T per head for PV MFMA B-operand
  transpose_v<<<dim3(4, 64, 4), 256, 0, stream>>>(vb, vtb);

  // flash attention -> attn (T x 2048 bf16)
  attn_kernel<<<dim3(64, 8), 256, 0, stream>>>(q_b, kb, vtb, attn);

  // output projection: (T x 2048) * (2048 x DM) -> o (f32) in d_out (160 blocks)
  gemm256<true><<<160, 512, 0, stream>>>(attn, woT, out + 2 * (size_t)T_TOK * NKV * HD,
                                         2048, 2048, 2048, DM);
}

// Round 10
// 268.237 us; speedup vs baseline: 1.7230x; 1.0060x over previous
//
#include <hip/hip_runtime.h>
#include <stdint.h>

// Problem constants (Gemma3 attention block)
#define T_TOK 4096
#define DM    2560
#define NQ    8
#define NKV   4
#define HD    256
#define WIN   1024

using bf16x8 = __attribute__((ext_vector_type(8))) short;
using f32x4  = __attribute__((ext_vector_type(4))) float;
typedef unsigned short u16;

__device__ __forceinline__ u16 f2bf(float x) {
  union { float f; uint32_t u; } v; v.f = x;
  uint32_t u = v.u;
  return (u16)((u + 0x7fffu + ((u >> 16) & 1u)) >> 16);  // RNE
}
__device__ __forceinline__ float bf2f(u16 b) {
  union { uint32_t u; float f; } v; v.u = ((uint32_t)b) << 16;
  return v.f;
}

// async global->LDS, 16B per lane. LDS dest is wave-uniform base; HW adds lane*16.
__device__ __forceinline__ void async_cp16(const void* g, void* lds) {
  __builtin_amdgcn_global_load_lds(
      (const __attribute__((address_space(1))) uint32_t*)(uintptr_t)g,
      (__attribute__((address_space(3))) uint32_t*)(uint32_t)(uintptr_t)lds,
      16, 0, 0);
}

// ---------------------------------------------------------------------------
// f32 -> bf16 elementwise convert (vectorized float4 loads)
__global__ __launch_bounds__(256) void convert_f32_bf16(
    const float* __restrict__ in, u16* __restrict__ out, int n)
{
  for (int i = (blockIdx.x * 256 + threadIdx.x) * 4; i < n; i += gridDim.x * 256 * 4) {
    float4 v = *(const float4*)(in + i);
    ushort4 o;
    o.x = f2bf(v.x); o.y = f2bf(v.y); o.z = f2bf(v.z); o.w = f2bf(v.w);
    *(ushort4*)(out + i) = o;
  }
}

// ---------------------------------------------------------------------------
// Tiled transpose + convert: in f32 (R x C) row-major -> out bf16 (C x R)
__global__ __launch_bounds__(256) void transpose_f32_bf16(
    const float* __restrict__ in, u16* __restrict__ out, int R, int C)
{
  __shared__ u16 tile[64][65];
  const int r0 = blockIdx.y * 64, c0 = blockIdx.x * 64;
  const int tr = threadIdx.x >> 6, tc = threadIdx.x & 63;
  #pragma unroll
  for (int i = 0; i < 16; ++i) {
    int r = tr + i * 4;
    tile[r][tc] = f2bf(in[(size_t)(r0 + r) * C + c0 + tc]);
  }
  __syncthreads();
  #pragma unroll
  for (int i = 0; i < 16; ++i) {
    int c = tr + i * 4;
    out[(size_t)(c0 + c) * R + r0 + tc] = tile[tc][c];
  }
}

// ---------------------------------------------------------------------------
// 256x256 bf16 GEMM, counted-vmcnt double-buffered pipeline.
// C(MxN) = A(MxK,row-major,lda) * B^T, B is (N x K,row-major,ldb).
// 8 waves (2Mx4N), BK=64, LDS 128 KiB. 1D grid, XCD-aware swizzle (GY=16).
template<bool F32OUT>
__global__ __launch_bounds__(512, 2) void gemm256(
    const u16* __restrict__ A, const u16* __restrict__ B, void* __restrict__ Cv,
    int Kd, int lda, int ldb, int ldc)
{
  __shared__ __align__(16) u16 lds[2][2][256 * 64];  // [buf][A|B] 128 KiB
  const int tid = threadIdx.x;
  const int wave = tid >> 6, lane = tid & 63;
  const int lg = lane >> 4, lc = lane & 15;
  const int wr = wave >> 2, wc = wave & 3;  // 2 x 4 wave grid
  // XCD swizzle: consecutive remapped ids cluster on one XCD, column-major
  const int nwg = gridDim.x, bid = blockIdx.x;
  const int nid = (bid & 7) * (nwg >> 3) + (bid >> 3);
  const int m0 = (nid & 15) * 256, n0 = (nid >> 4) * 256;
  const int NT = Kd >> 6;

  const int srow = tid >> 3;
  const int scol = ((tid & 7) * 16) ^ ((srow & 7) << 4);  // pre-swizzled source col
  const u16* Ag = A + (size_t)(m0 + srow) * lda + (scol >> 1);
  const u16* Bg = B + (size_t)(n0 + srow) * ldb + (scol >> 1);
  char* ldsA0 = (char*)&lds[0][0][0];
  char* ldsB0 = (char*)&lds[0][1][0];
  char* ldsA1 = (char*)&lds[1][0][0];
  char* ldsB1 = (char*)&lds[1][1][0];

  #define STAGE256(LA, LB, KT) do {                                         \
    const int kc_ = (KT) * 64;                                              \
    _Pragma("unroll")                                                       \
    for (int li = 0; li < 4; ++li)                                          \
      async_cp16(Ag + (size_t)(li * 64) * lda + kc_, (LA) + li * 8192 + wave * 1024); \
    _Pragma("unroll")                                                       \
    for (int li = 0; li < 4; ++li)                                          \
      async_cp16(Bg + (size_t)(li * 64) * ldb + kc_, (LB) + li * 8192 + wave * 1024); \
  } while (0)

  const f32x4 zf = {0.f, 0.f, 0.f, 0.f};
  f32x4 acc[8][4];
  #pragma unroll
  for (int i = 0; i < 8; ++i)
    #pragma unroll
    for (int j = 0; j < 4; ++j) acc[i][j] = zf;

  STAGE256(ldsA0, ldsB0, 0);
  STAGE256(ldsA1, ldsB1, 1);
  asm volatile("s_waitcnt vmcnt(8)" ::: "memory");
  __builtin_amdgcn_s_barrier();
  __builtin_amdgcn_sched_barrier(0);

  for (int t = 0; t < NT; ++t) {
    const int cur = t & 1;
    const u16* Ab = &lds[cur][0][0];
    const u16* Bb = &lds[cur][1][0];

    bf16x8 bf[4][2];
    #pragma unroll
    for (int j = 0; j < 4; ++j)
      #pragma unroll
      for (int k2 = 0; k2 < 2; ++k2) {
        const int row = wc * 64 + j * 16 + lc;
        const int cb = k2 * 64 + lg * 16;
        bf[j][k2] = *(const bf16x8*)((const char*)Bb + row * 128 + (cb ^ ((row & 7) << 4)));
      }

    #pragma unroll
    for (int p = 0; p < 4; ++p) {
      bf16x8 af[2][2];
      #pragma unroll
      for (int im = 0; im < 2; ++im)
        #pragma unroll
        for (int k2 = 0; k2 < 2; ++k2) {
          const int row = wr * 128 + (p * 2 + im) * 16 + lc;
          const int cb = k2 * 64 + lg * 16;
          af[im][k2] = *(const bf16x8*)((const char*)Ab + row * 128 + (cb ^ ((row & 7) << 4)));
        }
      __builtin_amdgcn_s_setprio(1);
      #pragma unroll
      for (int im = 0; im < 2; ++im)
        #pragma unroll
        for (int j = 0; j < 4; ++j)
          #pragma unroll
          for (int k2 = 0; k2 < 2; ++k2)
            acc[p * 2 + im][j] = __builtin_amdgcn_mfma_f32_16x16x32_bf16(
                af[im][k2], bf[j][k2], acc[p * 2 + im][j], 0, 0, 0);
      __builtin_amdgcn_s_setprio(0);
    }

    __builtin_amdgcn_s_barrier();
    __builtin_amdgcn_sched_barrier(0);
    int nk = t + 2; if (nk > NT - 1) nk = NT - 1;
    if (cur == 0) { STAGE256(ldsA0, ldsB0, nk); } else { STAGE256(ldsA1, ldsB1, nk); }
    asm volatile("s_waitcnt vmcnt(8)" ::: "memory");
    __builtin_amdgcn_s_barrier();
    __builtin_amdgcn_sched_barrier(0);
  }
  #undef STAGE256

  #pragma unroll
  for (int i = 0; i < 8; ++i)
    #pragma unroll
    for (int j = 0; j < 4; ++j)
      #pragma unroll
      for (int r = 0; r < 4; ++r) {
        const int row = m0 + wr * 128 + i * 16 + lg * 4 + r;
        const int col = n0 + wc * 64 + j * 16 + lc;
        if (F32OUT) ((float*)Cv)[(size_t)row * ldc + col] = acc[i][j][r];
        else        ((u16*)Cv)[(size_t)row * ldc + col] = f2bf(acc[i][j][r]);
      }
}

// ---------------------------------------------------------------------------
// Fused RMSNorm + query-scale + RoPE. Reads qkv (T x 4096 bf16):
// cols [0,2048) = q (n-major), [2048,3072) = k, [3072,4096) = v.
__global__ __launch_bounds__(256) void fuse_norm_rope(
    const u16* __restrict__ qkv, const float* __restrict__ qnw, const float* __restrict__ knw,
    const int* __restrict__ pos, u16* __restrict__ qb, u16* __restrict__ kb,
    u16* __restrict__ vb, float* __restrict__ kvout)
{
  const int t = blockIdx.x;
  const int wave = threadIdx.x >> 6, lane = threadIdx.x & 63;
  const float p = (float)pos[t];
  const float kf = 0.10381025296523007f;  // log2(10000)/128
  float s0, c0, s1, c1;
  sincosf(p * exp2f(-(float)lane * kf), &s0, &c0);
  sincosf(p * exp2f(-(float)(lane + 64) * kf), &s1, &c1);
  const u16* row = qkv + (size_t)t * 4096;

  for (int pp = 0; pp < 4; ++pp) {
    const int hr = pp * 4 + wave;  // 0..7 q, 8..11 k, 12..15 v
    if (hr >= 12) {
      const int kk = hr - 12;
      const u16* src = row + 3072 + kk * 256;
      float* dstf = kvout + (size_t)T_TOK * NKV * HD + ((size_t)t * NKV + kk) * HD;
      u16*   dstb = vb + ((size_t)t * NKV + kk) * HD;
      #pragma unroll
      for (int q4 = 0; q4 < 4; ++q4) {
        const u16 s = src[lane + q4 * 64];
        dstf[lane + q4 * 64] = bf2f(s);
        dstb[lane + q4 * 64] = s;
      }
    } else {
      const bool isq = hr < 8;
      const int cb = isq ? hr * 256 : 2048 + (hr - 8) * 256;
      float v0 = bf2f(row[cb + lane]);
      float v1 = bf2f(row[cb + lane + 64]);
      float v2 = bf2f(row[cb + lane + 128]);
      float v3 = bf2f(row[cb + lane + 192]);
      float ss = v0 * v0 + v1 * v1 + v2 * v2 + v3 * v3;
      #pragma unroll
      for (int off = 1; off < 64; off <<= 1) ss += __shfl_xor(ss, off);
      float sc = rsqrtf(ss * (1.0f / 256.0f) + 1e-6f);
      if (isq) sc *= 0.0625f;  // QUERY_PRE_ATTN_SCALAR^-0.5
      const float* wn = isq ? qnw : knw;
      v0 *= sc * wn[lane];
      v1 *= sc * wn[lane + 64];
      v2 *= sc * wn[lane + 128];
      v3 *= sc * wn[lane + 192];
      const float n0 = v0 * c0 - v2 * s0;
      const float n2 = v2 * c0 + v0 * s0;
      const float n1 = v1 * c1 - v3 * s1;
      const float n3 = v3 * c1 + v1 * s1;
      if (isq) {
        u16* dst = qb + (size_t)t * 2048 + hr * 256;
        dst[lane]       = f2bf(n0);
        dst[lane + 64]  = f2bf(n1);
        dst[lane + 128] = f2bf(n2);
        dst[lane + 192] = f2bf(n3);
      } else {
        const int kk = hr - 8;
        float* dstf = kvout + ((size_t)t * NKV + kk) * HD;
        dstf[lane]       = n0;
        dstf[lane + 64]  = n1;
        dstf[lane + 128] = n2;
        dstf[lane + 192] = n3;
        u16* dstb = kb + ((size_t)t * NKV + kk) * HD;
        dstb[lane]       = f2bf(n0);
        dstb[lane + 64]  = f2bf(n1);
        dstb[lane + 128] = f2bf(n2);
        dstb[lane + 192] = f2bf(n3);
      }
    }
  }
}

// ---------------------------------------------------------------------------
// Per-head V transpose: vb (T x NKV x HD bf16) -> vt (NKV x HD x T bf16)
__global__ __launch_bounds__(256) void transpose_v(
    const u16* __restrict__ vc, u16* __restrict__ vt)
{
  __shared__ u16 tile[64][65];
  const int kk = blockIdx.z;
  const int t0 = blockIdx.y * 64, h0 = blockIdx.x * 64;
  const int tr = threadIdx.x >> 6, tc = threadIdx.x & 63;
  #pragma unroll
  for (int i = 0; i < 16; ++i) {
    int tt = tr + i * 4;
    tile[tt][tc] = vc[((size_t)(t0 + tt) * NKV + kk) * HD + h0 + tc];
  }
  __syncthreads();
  #pragma unroll
  for (int i = 0; i < 16; ++i) {
    int h = tr + i * 4;
    vt[(size_t)kk * HD * T_TOK + (size_t)(h0 + h) * T_TOK + t0 + tc] = tile[tc][h];
  }
}

// ---------------------------------------------------------------------------
// Flash attention v5: 2 q-heads per block (one kv head), double-buffered
// global_load_lds K/V staging (latency hidden under compute), wave-local
// softmax, per-wave private P slice, ONE barrier per tile.
// LDS: 2x32K (K) + 2x32K (V) + 16K (P) = 144 KB -> 1 block/CU, 8 waves.
__global__ __launch_bounds__(512, 1) void attn_kernel(
    const u16* __restrict__ qb, const u16* __restrict__ kc,
    const u16* __restrict__ vt, u16* __restrict__ ob)
{
  __shared__ __align__(16) u16 Ks[2][64 * 256];    // [buf][key][d] swz
  __shared__ __align__(16) u16 Vts[2][256 * 64];   // [buf][d][key] swz
  __shared__ __align__(16) u16 Ps[8][16 * 64];     // per-wave [qrow][key] swz

  const int kk = blockIdx.y;             // kv head
  const int t0 = blockIdx.x * 64;
  const int tid = threadIdx.x;
  const int wave = tid >> 6, lane = tid & 63;
  const int lg = lane >> 4, lc = lane & 15;
  const int hq = kk * 2 + (wave >> 2);   // q head for this wave
  const int wrow = (wave & 3) * 16;      // q-row base within 64-row block
  const int lswz = (lc & 7) << 4;
  const f32x4 zf = {0.f, 0.f, 0.f, 0.f};

  // staging geometry (512 threads): K 4 issues x 16 rows, V 4 issues x 64 rows
  const int lrowK = tid >> 5;                        // 0..15
  const int scolK = ((tid & 31) * 16) ^ ((lrowK & 7) << 4);
  const int lrowV = tid >> 3;                        // 0..63
  const int scolV = ((tid & 7) * 16) ^ ((lrowV & 7) << 4);

  #define STAGEKV(KT, BUF) do {                                                \
    const int kb_ = (KT) * 64;                                                 \
    const u16* kp_ = kc + (size_t)(kb_ + lrowK) * (NKV * HD) + kk * HD + (scolK >> 1); \
    _Pragma("unroll")                                                          \
    for (int is = 0; is < 4; ++is)                                             \
      async_cp16(kp_ + (size_t)(is * 16) * (NKV * HD),                         \
                 (char*)&Ks[BUF][0] + is * 8192 + wave * 1024);                \
    const u16* vp_ = vt + (size_t)kk * (HD * T_TOK) + (size_t)lrowV * T_TOK + kb_ + (scolV >> 1); \
    _Pragma("unroll")                                                          \
    for (int is = 0; is < 4; ++is)                                             \
      async_cp16(vp_ + (size_t)(is * 64) * T_TOK,                              \
                 (char*)&Vts[BUF][0] + is * 8192 + wave * 1024);               \
  } while (0)

  // Q fragments straight from global (rows t0+wrow+lc of head hq)
  bf16x8 qf[8];
  {
    const u16* qp = qb + (size_t)(t0 + wrow + lc) * 2048 + hq * 256 + lg * 8;
    #pragma unroll
    for (int ks = 0; ks < 8; ++ks) qf[ks] = *(const bf16x8*)(qp + ks * 32);
  }

  f32x4 o_acc[16];
  #pragma unroll
  for (int j = 0; j < 16; ++j) o_acc[j] = zf;
  float m_r[4], l_r[4];
  #pragma unroll
  for (int r = 0; r < 4; ++r) { m_r[r] = -1e30f; l_r[r] = 0.f; }

  const int mtile = t0 >> 6;
  const int ktf = (mtile >= 16) ? (mtile - 16) : 0;

  // prologue: stage first tile into buf 0 (drain via syncthreads)
  STAGEKV(ktf, 0);
  __syncthreads();

  int cur = 0;
  for (int kt = ktf; kt <= mtile; ++kt) {
    const int kb = kt * 64;
    // issue next tile's staging into the other buffer (lands under compute)
    if (kt < mtile) STAGEKV(kt + 1, cur ^ 1);

    const u16* Kb = &Ks[cur][0];
    const u16* Vb = &Vts[cur][0];

    // ---- S = Q K^T : this wave's 16 rows x 64 keys
    f32x4 sf[4];
    #pragma unroll
    for (int j = 0; j < 4; ++j) sf[j] = zf;
    __builtin_amdgcn_s_setprio(1);
    #pragma unroll
    for (int ks = 0; ks < 8; ++ks)
      #pragma unroll
      for (int j = 0; j < 4; ++j) {
        const int row = j * 16 + lc;
        bf16x8 kf = *(const bf16x8*)((const char*)Kb + ((row * 512 + ks * 64 + lg * 16) ^ lswz));
        sf[j] = __builtin_amdgcn_mfma_f32_16x16x32_bf16(qf[ks], kf, sf[j], 0, 0, 0);
      }
    __builtin_amdgcn_s_setprio(0);

    // ---- mask (skip fully-interior tiles)
    const bool interior = (kb >= t0 - 960) && (kb <= t0 - 64);
    if (!interior) {
      #pragma unroll
      for (int j = 0; j < 4; ++j) {
        const int gcol = kb + j * 16 + lc;
        #pragma unroll
        for (int r = 0; r < 4; ++r) {
          const int grow = t0 + wrow + lg * 4 + r;
          if ((unsigned)(grow - gcol) >= WIN) sf[j][r] = -1e30f;
        }
      }
    }

    // ---- wave-local online softmax (rows lg*4+r, reduce over 16 lc lanes)
    float a_r[4];
    #pragma unroll
    for (int r = 0; r < 4; ++r) {
      float v = fmaxf(fmaxf(sf[0][r], sf[1][r]), fmaxf(sf[2][r], sf[3][r]));
      v = fmaxf(v, __shfl_xor(v, 1));
      v = fmaxf(v, __shfl_xor(v, 2));
      v = fmaxf(v, __shfl_xor(v, 4));
      v = fmaxf(v, __shfl_xor(v, 8));
      const float mn = fmaxf(m_r[r], v);
      a_r[r] = __expf(m_r[r] - mn);
      m_r[r] = mn;
    }

    // ---- P = exp(S-m) -> own LDS slice; row sums; l update
    char* myP = (char*)&Ps[wave][0];
    #pragma unroll
    for (int r = 0; r < 4; ++r) {
      const int row = lg * 4 + r;
      const int rsw = (row & 7) << 4;
      float su = 0.f;
      #pragma unroll
      for (int j = 0; j < 4; ++j) {
        const float p = __expf(sf[j][r] - m_r[r]);
        su += p;
        *(u16*)(myP + ((row * 128 + (j * 16 + lc) * 2) ^ rsw)) = f2bf(p);
      }
      su += __shfl_xor(su, 1);
      su += __shfl_xor(su, 2);
      su += __shfl_xor(su, 4);
      su += __shfl_xor(su, 8);
      l_r[r] = l_r[r] * a_r[r] + su;
    }

    // ---- rescale O
    #pragma unroll
    for (int j = 0; j < 16; ++j) {
      o_acc[j][0] *= a_r[0];
      o_acc[j][1] *= a_r[1];
      o_acc[j][2] *= a_r[2];
      o_acc[j][3] *= a_r[3];
    }

    // ---- O += P * V (P read is wave-private: lgkmcnt only, no barrier)
    bf16x8 pa[2];
    #pragma unroll
    for (int ks = 0; ks < 2; ++ks)
      pa[ks] = *(const bf16x8*)(myP + ((lc * 128 + ks * 64 + lg * 16) ^ lswz));
    __builtin_amdgcn_s_setprio(1);
    #pragma unroll
    for (int ks = 0; ks < 2; ++ks)
      #pragma unroll
      for (int j = 0; j < 16; ++j) {
        const int row = j * 16 + lc;
        bf16x8 vf = *(const bf16x8*)((const char*)Vb + ((row * 128 + ks * 64 + lg * 16) ^ lswz));
        o_acc[j] = __builtin_amdgcn_mfma_f32_16x16x32_bf16(pa[ks], vf, o_acc[j], 0, 0, 0);
      }
    __builtin_amdgcn_s_setprio(0);

    // single barrier: releases buf[cur] for restaging AND (implicit vmcnt
    // drain) guarantees tile kt+1 landed in buf[cur^1] for all waves
    __syncthreads();
    cur ^= 1;
  }
  #undef STAGEKV

  // ---- epilogue: O / l -> attn buffer (T x 2048 bf16)
  #pragma unroll
  for (int r = 0; r < 4; ++r) {
    const float li = 1.f / l_r[r];
    const size_t rowb = (size_t)(t0 + wrow + lg * 4 + r) * 2048 + hq * 256 + lc;
    #pragma unroll
    for (int j = 0; j < 16; ++j)
      ob[rowb + j * 16] = f2bf(o_acc[j][r] * li);
  }
}

// ---------------------------------------------------------------------------
extern "C" void kernel_launch(void* const* d_in, const int* in_sizes, int n_in,
                              void* d_out, int out_size, void* d_ws, size_t ws_size,
                              hipStream_t stream)
{
  (void)in_sizes; (void)n_in; (void)out_size; (void)ws_size;
  const float* x   = (const float*)d_in[0];
  const float* wq  = (const float*)d_in[1];
  const float* wk  = (const float*)d_in[2];
  const float* wv  = (const float*)d_in[3];
  const float* wo  = (const float*)d_in[4];
  const float* qnw = (const float*)d_in[5];
  const float* knw = (const float*)d_in[6];
  const int*   pos = (const int*)d_in[7];
  float* out = (float*)d_out;  // f32: [2*T*NKV*HD kv cache][T*DM o]

  // workspace layout (peak 86 MB), lifetime-aliased
  char* ws = (char*)d_ws;
  u16* woT   = (u16*)(ws);                    // 2560x2048 bf16 (10.5 MB), live to end
  u16* xb    = (u16*)(ws + 10485760);         // T x DM bf16 (21.0 MB)
  u16* wqkvT = (u16*)(ws + 31457280);         // 4096 x DM bf16 (21.0 MB)
  u16* qkv   = (u16*)(ws + 52428800);         // T x 4096 bf16 (33.6 MB)
  u16* q_b   = xb;                            // alias: xb dead after gemm1 (16.8 MB)
  u16* kb    = wqkvT;                         // alias: wqkvT dead after gemm1 (8.4 MB)
  u16* vb    = (u16*)(ws + 31457280 + 8388608); // (8.4 MB, still inside wqkvT)
  u16* vtb   = qkv;                           // alias: qkv dead after fuse (8.4 MB)
  u16* attn  = (u16*)(ws + 52428800 + 8388608); // (16.8 MB, inside qkv region)

  convert_f32_bf16<<<2048, 256, 0, stream>>>(x, xb, T_TOK * DM);
  transpose_f32_bf16<<<dim3(32, 40), 256, 0, stream>>>(wq, wqkvT, DM, 2048);
  transpose_f32_bf16<<<dim3(16, 40), 256, 0, stream>>>(wk, wqkvT + 2048 * DM, DM, 1024);
  transpose_f32_bf16<<<dim3(16, 40), 256, 0, stream>>>(wv, wqkvT + 3072 * DM, DM, 1024);
  transpose_f32_bf16<<<dim3(40, 32), 256, 0, stream>>>(wo, woT, 2048, DM);

  // QKV projection: (T x DM) * (DM x 4096) -> T x 4096 bf16 (256 blocks, XCD-swz)
  gemm256<false><<<256, 512, 0, stream>>>(xb, wqkvT, qkv, DM, DM, DM, 4096);

  // RMSNorm + scale + RoPE; k/v f32 into kv cache (d_out) + bf16 copies
  fuse_norm_rope<<<T_TOK, 256, 0, stream>>>(qkv, qnw, knw, pos, q_b, kb, vb, out);

  // V^T per head for PV MFMA B-operand
  transpose_v<<<dim3(4, 64, 4), 256, 0, stream>>>(vb, vtb);

  // flash attention: 64-row q-block x kv-head (2 q heads) -> attn (T x 2048)
  attn_kernel<<<dim3(64, 4), 512, 0, stream>>>(q_b, kb, vtb, attn);

  // output projection: (T x 2048) * (2048 x DM) -> o (f32) in d_out (160 blocks)
  gemm256<true><<<160, 512, 0, stream>>>(attn, woT, out + 2 * (size_t)T_TOK * NKV * HD,
                                         2048, 2048, 2048, DM);
}

// Round 11
// 262.936 us; speedup vs baseline: 1.7578x; 1.0202x over previous
//
#include <hip/hip_runtime.h>
#include <stdint.h>

// Problem constants (Gemma3 attention block)
#define T_TOK 4096
#define DM    2560
#define NQ    8
#define NKV   4
#define HD    256
#define WIN   1024

using bf16x8 = __attribute__((ext_vector_type(8))) short;
using f32x4  = __attribute__((ext_vector_type(4))) float;
typedef unsigned short u16;

__device__ __forceinline__ u16 f2bf(float x) {
  union { float f; uint32_t u; } v; v.f = x;
  uint32_t u = v.u;
  return (u16)((u + 0x7fffu + ((u >> 16) & 1u)) >> 16);  // RNE
}
__device__ __forceinline__ float bf2f(u16 b) {
  union { uint32_t u; float f; } v; v.u = ((uint32_t)b) << 16;
  return v.f;
}

// async global->LDS, 16B per lane. LDS dest is wave-uniform base; HW adds lane*16.
__device__ __forceinline__ void async_cp16(const void* g, void* lds) {
  __builtin_amdgcn_global_load_lds(
      (const __attribute__((address_space(1))) uint32_t*)(uintptr_t)g,
      (__attribute__((address_space(3))) uint32_t*)(uint32_t)(uintptr_t)lds,
      16, 0, 0);
}

// ---------------------------------------------------------------------------
// f32 -> bf16 elementwise convert (vectorized float4 loads)
__global__ __launch_bounds__(256) void convert_f32_bf16(
    const float* __restrict__ in, u16* __restrict__ out, int n)
{
  for (int i = (blockIdx.x * 256 + threadIdx.x) * 4; i < n; i += gridDim.x * 256 * 4) {
    float4 v = *(const float4*)(in + i);
    ushort4 o;
    o.x = f2bf(v.x); o.y = f2bf(v.y); o.z = f2bf(v.z); o.w = f2bf(v.w);
    *(ushort4*)(out + i) = o;
  }
}

// ---------------------------------------------------------------------------
// Tiled transpose + convert: in f32 (R x C) row-major -> out bf16 (C x R)
__global__ __launch_bounds__(256) void transpose_f32_bf16(
    const float* __restrict__ in, u16* __restrict__ out, int R, int C)
{
  __shared__ u16 tile[64][65];
  const int r0 = blockIdx.y * 64, c0 = blockIdx.x * 64;
  const int tr = threadIdx.x >> 6, tc = threadIdx.x & 63;
  #pragma unroll
  for (int i = 0; i < 16; ++i) {
    int r = tr + i * 4;
    tile[r][tc] = f2bf(in[(size_t)(r0 + r) * C + c0 + tc]);
  }
  __syncthreads();
  #pragma unroll
  for (int i = 0; i < 16; ++i) {
    int c = tr + i * 4;
    out[(size_t)(c0 + c) * R + r0 + tc] = tile[tc][c];
  }
}

// ---------------------------------------------------------------------------
// BMxBN bf16 GEMM, counted-vmcnt double-buffered pipeline (schedule identical
// to the verified 256x256 kernel; tile dims templated).
// C(MxN) = A(MxK,row-major,lda) * B^T, B is (N x K,row-major,ldb).
// 8 waves (2Mx4N), BK=64. Per-wave: (BM/2) x (BN/4). 1D grid, XCD swizzle.
template<int BM, int BN, bool F32OUT>
__global__ __launch_bounds__(512, 2) void gemm_t(
    const u16* __restrict__ A, const u16* __restrict__ B, void* __restrict__ Cv,
    int Kd, int lda, int ldb, int ldc, int MT)
{
  constexpr int MF = BM / 32;         // m-frags per wave
  constexpr int NF = BN / 64;         // n-frags per wave
  constexpr int ISS = (BM + BN) / 64; // stage issues per K-tile (8KB each)
  constexpr int AISS = BM / 64;       // of which A
  __shared__ __align__(16) u16 lds[2][(BM + BN) * 64];  // [buf][A rows | B rows]
  const int tid = threadIdx.x;
  const int wave = tid >> 6, lane = tid & 63;
  const int lg = lane >> 4, lc = lane & 15;
  const int wr = wave >> 2, wc = wave & 3;  // 2 x 4 wave grid
  // XCD swizzle (bijective: gridDim.x % 8 == 0)
  const int nwg = gridDim.x, bid = blockIdx.x;
  const int nid = (bid & 7) * (nwg >> 3) + (bid >> 3);
  const int m0 = (nid % MT) * BM, n0 = (nid / MT) * BN;
  const int NT = Kd >> 6;

  const int srow = tid >> 3;  // 0..63 (+64*li per issue; 64%8==0 keeps swz valid)
  const int scol = ((tid & 7) * 16) ^ ((srow & 7) << 4);  // pre-swizzled source col
  const u16* Ag = A + (size_t)(m0 + srow) * lda + (scol >> 1);
  const u16* Bg = B + (size_t)(n0 + srow) * ldb + (scol >> 1);
  char* lds0 = (char*)&lds[0][0];
  char* lds1 = (char*)&lds[1][0];

  #define STAGE_T(LD, KT) do {                                              \
    const int kc_ = (KT) * 64;                                              \
    _Pragma("unroll")                                                       \
    for (int li = 0; li < ISS; ++li) {                                      \
      if (li < AISS)                                                        \
        async_cp16(Ag + (size_t)(li * 64) * lda + kc_,                      \
                   (LD) + li * 8192 + wave * 1024);                         \
      else                                                                  \
        async_cp16(Bg + (size_t)((li - AISS) * 64) * ldb + kc_,             \
                   (LD) + li * 8192 + wave * 1024);                         \
    }                                                                       \
  } while (0)

  #define WAIT_ISS() do {                                                   \
    if (ISS == 8) asm volatile("s_waitcnt vmcnt(8)" ::: "memory");          \
    else          asm volatile("s_waitcnt vmcnt(7)" ::: "memory");          \
  } while (0)

  const f32x4 zf = {0.f, 0.f, 0.f, 0.f};
  f32x4 acc[MF][NF];
  #pragma unroll
  for (int i = 0; i < MF; ++i)
    #pragma unroll
    for (int j = 0; j < NF; ++j) acc[i][j] = zf;

  STAGE_T(lds0, 0);
  STAGE_T(lds1, 1);
  WAIT_ISS();
  __builtin_amdgcn_s_barrier();
  __builtin_amdgcn_sched_barrier(0);

  for (int t = 0; t < NT; ++t) {
    const int cur = t & 1;
    const char* Ab = cur ? lds1 : lds0;
    const char* Bb = Ab + BM * 128;

    bf16x8 bf[NF][2];
    #pragma unroll
    for (int j = 0; j < NF; ++j)
      #pragma unroll
      for (int k2 = 0; k2 < 2; ++k2) {
        const int row = wc * (BN / 4) + j * 16 + lc;
        const int cb = k2 * 64 + lg * 16;
        bf[j][k2] = *(const bf16x8*)(Bb + row * 128 + (cb ^ ((row & 7) << 4)));
      }

    #pragma unroll
    for (int p = 0; p < MF / 2; ++p) {
      bf16x8 af[2][2];
      #pragma unroll
      for (int im = 0; im < 2; ++im)
        #pragma unroll
        for (int k2 = 0; k2 < 2; ++k2) {
          const int row = wr * (BM / 2) + (p * 2 + im) * 16 + lc;
          const int cb = k2 * 64 + lg * 16;
          af[im][k2] = *(const bf16x8*)(Ab + row * 128 + (cb ^ ((row & 7) << 4)));
        }
      __builtin_amdgcn_s_setprio(1);
      #pragma unroll
      for (int im = 0; im < 2; ++im)
        #pragma unroll
        for (int j = 0; j < NF; ++j)
          #pragma unroll
          for (int k2 = 0; k2 < 2; ++k2)
            acc[p * 2 + im][j] = __builtin_amdgcn_mfma_f32_16x16x32_bf16(
                af[im][k2], bf[j][k2], acc[p * 2 + im][j], 0, 0, 0);
      __builtin_amdgcn_s_setprio(0);
    }

    __builtin_amdgcn_s_barrier();
    __builtin_amdgcn_sched_barrier(0);
    int nk = t + 2; if (nk > NT - 1) nk = NT - 1;  // clamped restage, uniform ledger
    if (cur == 0) { STAGE_T(lds0, nk); } else { STAGE_T(lds1, nk); }
    WAIT_ISS();
    __builtin_amdgcn_s_barrier();
    __builtin_amdgcn_sched_barrier(0);
  }
  #undef STAGE_T
  #undef WAIT_ISS

  #pragma unroll
  for (int i = 0; i < MF; ++i)
    #pragma unroll
    for (int j = 0; j < NF; ++j)
      #pragma unroll
      for (int r = 0; r < 4; ++r) {
        const int row = m0 + wr * (BM / 2) + i * 16 + lg * 4 + r;
        const int col = n0 + wc * (BN / 4) + j * 16 + lc;
        if (F32OUT) ((float*)Cv)[(size_t)row * ldc + col] = acc[i][j][r];
        else        ((u16*)Cv)[(size_t)row * ldc + col] = f2bf(acc[i][j][r]);
      }
}

// ---------------------------------------------------------------------------
// Fused RMSNorm + query-scale + RoPE. Reads qkv (T x 4096 bf16):
// cols [0,2048) = q (n-major), [2048,3072) = k, [3072,4096) = v.
__global__ __launch_bounds__(256) void fuse_norm_rope(
    const u16* __restrict__ qkv, const float* __restrict__ qnw, const float* __restrict__ knw,
    const int* __restrict__ pos, u16* __restrict__ qb, u16* __restrict__ kb,
    u16* __restrict__ vb, float* __restrict__ kvout)
{
  const int t = blockIdx.x;
  const int wave = threadIdx.x >> 6, lane = threadIdx.x & 63;
  const float p = (float)pos[t];
  const float kf = 0.10381025296523007f;  // log2(10000)/128
  float s0, c0, s1, c1;
  sincosf(p * exp2f(-(float)lane * kf), &s0, &c0);
  sincosf(p * exp2f(-(float)(lane + 64) * kf), &s1, &c1);
  const u16* row = qkv + (size_t)t * 4096;

  for (int pp = 0; pp < 4; ++pp) {
    const int hr = pp * 4 + wave;  // 0..7 q, 8..11 k, 12..15 v
    if (hr >= 12) {
      const int kk = hr - 12;
      const u16* src = row + 3072 + kk * 256;
      float* dstf = kvout + (size_t)T_TOK * NKV * HD + ((size_t)t * NKV + kk) * HD;
      u16*   dstb = vb + ((size_t)t * NKV + kk) * HD;
      #pragma unroll
      for (int q4 = 0; q4 < 4; ++q4) {
        const u16 s = src[lane + q4 * 64];
        dstf[lane + q4 * 64] = bf2f(s);
        dstb[lane + q4 * 64] = s;
      }
    } else {
      const bool isq = hr < 8;
      const int cb = isq ? hr * 256 : 2048 + (hr - 8) * 256;
      float v0 = bf2f(row[cb + lane]);
      float v1 = bf2f(row[cb + lane + 64]);
      float v2 = bf2f(row[cb + lane + 128]);
      float v3 = bf2f(row[cb + lane + 192]);
      float ss = v0 * v0 + v1 * v1 + v2 * v2 + v3 * v3;
      #pragma unroll
      for (int off = 1; off < 64; off <<= 1) ss += __shfl_xor(ss, off);
      float sc = rsqrtf(ss * (1.0f / 256.0f) + 1e-6f);
      if (isq) sc *= 0.0625f;  // QUERY_PRE_ATTN_SCALAR^-0.5
      const float* wn = isq ? qnw : knw;
      v0 *= sc * wn[lane];
      v1 *= sc * wn[lane + 64];
      v2 *= sc * wn[lane + 128];
      v3 *= sc * wn[lane + 192];
      const float n0 = v0 * c0 - v2 * s0;
      const float n2 = v2 * c0 + v0 * s0;
      const float n1 = v1 * c1 - v3 * s1;
      const float n3 = v3 * c1 + v1 * s1;
      if (isq) {
        u16* dst = qb + (size_t)t * 2048 + hr * 256;
        dst[lane]       = f2bf(n0);
        dst[lane + 64]  = f2bf(n1);
        dst[lane + 128] = f2bf(n2);
        dst[lane + 192] = f2bf(n3);
      } else {
        const int kk = hr - 8;
        float* dstf = kvout + ((size_t)t * NKV + kk) * HD;
        dstf[lane]       = n0;
        dstf[lane + 64]  = n1;
        dstf[lane + 128] = n2;
        dstf[lane + 192] = n3;
        u16* dstb = kb + ((size_t)t * NKV + kk) * HD;
        dstb[lane]       = f2bf(n0);
        dstb[lane + 64]  = f2bf(n1);
        dstb[lane + 128] = f2bf(n2);
        dstb[lane + 192] = f2bf(n3);
      }
    }
  }
}

// ---------------------------------------------------------------------------
// Per-head V transpose: vb (T x NKV x HD bf16) -> vt (NKV x HD x T bf16)
__global__ __launch_bounds__(256) void transpose_v(
    const u16* __restrict__ vc, u16* __restrict__ vt)
{
  __shared__ u16 tile[64][65];
  const int kk = blockIdx.z;
  const int t0 = blockIdx.y * 64, h0 = blockIdx.x * 64;
  const int tr = threadIdx.x >> 6, tc = threadIdx.x & 63;
  #pragma unroll
  for (int i = 0; i < 16; ++i) {
    int tt = tr + i * 4;
    tile[tt][tc] = vc[((size_t)(t0 + tt) * NKV + kk) * HD + h0 + tc];
  }
  __syncthreads();
  #pragma unroll
  for (int i = 0; i < 16; ++i) {
    int h = tr + i * 4;
    vt[(size_t)kk * HD * T_TOK + (size_t)(h0 + h) * T_TOK + t0 + tc] = tile[tc][h];
  }
}

// ---------------------------------------------------------------------------
// Flash attention v5: 2 q-heads per block (one kv head), double-buffered
// global_load_lds K/V staging, wave-local softmax, per-wave private P slice,
// one barrier per tile. LDS 144 KB -> 1 block/CU, 8 waves.
__global__ __launch_bounds__(512, 1) void attn_kernel(
    const u16* __restrict__ qb, const u16* __restrict__ kc,
    const u16* __restrict__ vt, u16* __restrict__ ob)
{
  __shared__ __align__(16) u16 Ks[2][64 * 256];    // [buf][key][d] swz
  __shared__ __align__(16) u16 Vts[2][256 * 64];   // [buf][d][key] swz
  __shared__ __align__(16) u16 Ps[8][16 * 64];     // per-wave [qrow][key] swz

  const int kk = blockIdx.y;             // kv head
  const int t0 = blockIdx.x * 64;
  const int tid = threadIdx.x;
  const int wave = tid >> 6, lane = tid & 63;
  const int lg = lane >> 4, lc = lane & 15;
  const int hq = kk * 2 + (wave >> 2);   // q head for this wave
  const int wrow = (wave & 3) * 16;      // q-row base within 64-row block
  const int lswz = (lc & 7) << 4;
  const f32x4 zf = {0.f, 0.f, 0.f, 0.f};

  // staging geometry (512 threads): K 4 issues x 16 rows, V 4 issues x 64 rows
  const int lrowK = tid >> 5;                        // 0..15
  const int scolK = ((tid & 31) * 16) ^ ((lrowK & 7) << 4);
  const int lrowV = tid >> 3;                        // 0..63
  const int scolV = ((tid & 7) * 16) ^ ((lrowV & 7) << 4);

  #define STAGEKV(KT, BUF) do {                                                \
    const int kb_ = (KT) * 64;                                                 \
    const u16* kp_ = kc + (size_t)(kb_ + lrowK) * (NKV * HD) + kk * HD + (scolK >> 1); \
    _Pragma("unroll")                                                          \
    for (int is = 0; is < 4; ++is)                                             \
      async_cp16(kp_ + (size_t)(is * 16) * (NKV * HD),                         \
                 (char*)&Ks[BUF][0] + is * 8192 + wave * 1024);                \
    const u16* vp_ = vt + (size_t)kk * (HD * T_TOK) + (size_t)lrowV * T_TOK + kb_ + (scolV >> 1); \
    _Pragma("unroll")                                                          \
    for (int is = 0; is < 4; ++is)                                             \
      async_cp16(vp_ + (size_t)(is * 64) * T_TOK,                              \
                 (char*)&Vts[BUF][0] + is * 8192 + wave * 1024);               \
  } while (0)

  // Q fragments straight from global (rows t0+wrow+lc of head hq)
  bf16x8 qf[8];
  {
    const u16* qp = qb + (size_t)(t0 + wrow + lc) * 2048 + hq * 256 + lg * 8;
    #pragma unroll
    for (int ks = 0; ks < 8; ++ks) qf[ks] = *(const bf16x8*)(qp + ks * 32);
  }

  f32x4 o_acc[16];
  #pragma unroll
  for (int j = 0; j < 16; ++j) o_acc[j] = zf;
  float m_r[4], l_r[4];
  #pragma unroll
  for (int r = 0; r < 4; ++r) { m_r[r] = -1e30f; l_r[r] = 0.f; }

  const int mtile = t0 >> 6;
  const int ktf = (mtile >= 16) ? (mtile - 16) : 0;

  // prologue: stage first tile into buf 0 (drain via syncthreads)
  STAGEKV(ktf, 0);
  __syncthreads();

  int cur = 0;
  for (int kt = ktf; kt <= mtile; ++kt) {
    const int kb = kt * 64;
    // issue next tile's staging into the other buffer (lands under compute)
    if (kt < mtile) STAGEKV(kt + 1, cur ^ 1);

    const u16* Kb = &Ks[cur][0];
    const u16* Vb = &Vts[cur][0];

    // ---- S = Q K^T : this wave's 16 rows x 64 keys
    f32x4 sf[4];
    #pragma unroll
    for (int j = 0; j < 4; ++j) sf[j] = zf;
    __builtin_amdgcn_s_setprio(1);
    #pragma unroll
    for (int ks = 0; ks < 8; ++ks)
      #pragma unroll
      for (int j = 0; j < 4; ++j) {
        const int row = j * 16 + lc;
        bf16x8 kf = *(const bf16x8*)((const char*)Kb + ((row * 512 + ks * 64 + lg * 16) ^ lswz));
        sf[j] = __builtin_amdgcn_mfma_f32_16x16x32_bf16(qf[ks], kf, sf[j], 0, 0, 0);
      }
    __builtin_amdgcn_s_setprio(0);

    // ---- mask (skip fully-interior tiles)
    const bool interior = (kb >= t0 - 960) && (kb <= t0 - 64);
    if (!interior) {
      #pragma unroll
      for (int j = 0; j < 4; ++j) {
        const int gcol = kb + j * 16 + lc;
        #pragma unroll
        for (int r = 0; r < 4; ++r) {
          const int grow = t0 + wrow + lg * 4 + r;
          if ((unsigned)(grow - gcol) >= WIN) sf[j][r] = -1e30f;
        }
      }
    }

    // ---- wave-local online softmax (rows lg*4+r, reduce over 16 lc lanes)
    float a_r[4];
    #pragma unroll
    for (int r = 0; r < 4; ++r) {
      float v = fmaxf(fmaxf(sf[0][r], sf[1][r]), fmaxf(sf[2][r], sf[3][r]));
      v = fmaxf(v, __shfl_xor(v, 1));
      v = fmaxf(v, __shfl_xor(v, 2));
      v = fmaxf(v, __shfl_xor(v, 4));
      v = fmaxf(v, __shfl_xor(v, 8));
      const float mn = fmaxf(m_r[r], v);
      a_r[r] = __expf(m_r[r] - mn);
      m_r[r] = mn;
    }

    // ---- P = exp(S-m) -> own LDS slice; row sums; l update
    char* myP = (char*)&Ps[wave][0];
    #pragma unroll
    for (int r = 0; r < 4; ++r) {
      const int row = lg * 4 + r;
      const int rsw = (row & 7) << 4;
      float su = 0.f;
      #pragma unroll
      for (int j = 0; j < 4; ++j) {
        const float p = __expf(sf[j][r] - m_r[r]);
        su += p;
        *(u16*)(myP + ((row * 128 + (j * 16 + lc) * 2) ^ rsw)) = f2bf(p);
      }
      su += __shfl_xor(su, 1);
      su += __shfl_xor(su, 2);
      su += __shfl_xor(su, 4);
      su += __shfl_xor(su, 8);
      l_r[r] = l_r[r] * a_r[r] + su;
    }

    // ---- rescale O
    #pragma unroll
    for (int j = 0; j < 16; ++j) {
      o_acc[j][0] *= a_r[0];
      o_acc[j][1] *= a_r[1];
      o_acc[j][2] *= a_r[2];
      o_acc[j][3] *= a_r[3];
    }

    // ---- O += P * V (P read is wave-private: lgkmcnt only, no barrier)
    bf16x8 pa[2];
    #pragma unroll
    for (int ks = 0; ks < 2; ++ks)
      pa[ks] = *(const bf16x8*)(myP + ((lc * 128 + ks * 64 + lg * 16) ^ lswz));
    __builtin_amdgcn_s_setprio(1);
    #pragma unroll
    for (int ks = 0; ks < 2; ++ks)
      #pragma unroll
      for (int j = 0; j < 16; ++j) {
        const int row = j * 16 + lc;
        bf16x8 vf = *(const bf16x8*)((const char*)Vb + ((row * 128 + ks * 64 + lg * 16) ^ lswz));
        o_acc[j] = __builtin_amdgcn_mfma_f32_16x16x32_bf16(pa[ks], vf, o_acc[j], 0, 0, 0);
      }
    __builtin_amdgcn_s_setprio(0);

    // single barrier: releases buf[cur] for restaging AND (implicit vmcnt
    // drain) guarantees tile kt+1 landed in buf[cur^1] for all waves
    __syncthreads();
    cur ^= 1;
  }
  #undef STAGEKV

  // ---- epilogue: O / l -> attn buffer (T x 2048 bf16)
  #pragma unroll
  for (int r = 0; r < 4; ++r) {
    const float li = 1.f / l_r[r];
    const size_t rowb = (size_t)(t0 + wrow + lg * 4 + r) * 2048 + hq * 256 + lc;
    #pragma unroll
    for (int j = 0; j < 16; ++j)
      ob[rowb + j * 16] = f2bf(o_acc[j][r] * li);
  }
}

// ---------------------------------------------------------------------------
extern "C" void kernel_launch(void* const* d_in, const int* in_sizes, int n_in,
                              void* d_out, int out_size, void* d_ws, size_t ws_size,
                              hipStream_t stream)
{
  (void)in_sizes; (void)n_in; (void)out_size; (void)ws_size;
  const float* x   = (const float*)d_in[0];
  const float* wq  = (const float*)d_in[1];
  const float* wk  = (const float*)d_in[2];
  const float* wv  = (const float*)d_in[3];
  const float* wo  = (const float*)d_in[4];
  const float* qnw = (const float*)d_in[5];
  const float* knw = (const float*)d_in[6];
  const int*   pos = (const int*)d_in[7];
  float* out = (float*)d_out;  // f32: [2*T*NKV*HD kv cache][T*DM o]

  // workspace layout (peak 86 MB), lifetime-aliased
  char* ws = (char*)d_ws;
  u16* woT   = (u16*)(ws);                    // 2560x2048 bf16 (10.5 MB), live to end
  u16* xb    = (u16*)(ws + 10485760);         // T x DM bf16 (21.0 MB)
  u16* wqkvT = (u16*)(ws + 31457280);         // 4096 x DM bf16 (21.0 MB)
  u16* qkv   = (u16*)(ws + 52428800);         // T x 4096 bf16 (33.6 MB)
  u16* q_b   = xb;                            // alias: xb dead after gemm1 (16.8 MB)
  u16* kb    = wqkvT;                         // alias: wqkvT dead after gemm1 (8.4 MB)
  u16* vb    = (u16*)(ws + 31457280 + 8388608); // (8.4 MB, still inside wqkvT)
  u16* vtb   = qkv;                           // alias: qkv dead after fuse (8.4 MB)
  u16* attn  = (u16*)(ws + 52428800 + 8388608); // (16.8 MB, inside qkv region)

  convert_f32_bf16<<<2048, 256, 0, stream>>>(x, xb, T_TOK * DM);
  transpose_f32_bf16<<<dim3(32, 40), 256, 0, stream>>>(wq, wqkvT, DM, 2048);
  transpose_f32_bf16<<<dim3(16, 40), 256, 0, stream>>>(wk, wqkvT + 2048 * DM, DM, 1024);
  transpose_f32_bf16<<<dim3(16, 40), 256, 0, stream>>>(wv, wqkvT + 3072 * DM, DM, 1024);
  transpose_f32_bf16<<<dim3(40, 32), 256, 0, stream>>>(wo, woT, 2048, DM);

  // QKV projection: 256x256 tile, 256 blocks = 1/CU, XCD-swz
  gemm_t<256, 256, false><<<256, 512, 0, stream>>>(xb, wqkvT, qkv, DM, DM, DM, 4096, 16);

  // RMSNorm + scale + RoPE; k/v f32 into kv cache (d_out) + bf16 copies
  fuse_norm_rope<<<T_TOK, 256, 0, stream>>>(qkv, qnw, knw, pos, q_b, kb, vb, out);

  // V^T per head for PV MFMA B-operand
  transpose_v<<<dim3(4, 64, 4), 256, 0, stream>>>(vb, vtb);

  // flash attention: 64-row q-block x kv-head (2 q heads) -> attn (T x 2048)
  attn_kernel<<<dim3(64, 4), 512, 0, stream>>>(q_b, kb, vtb, attn);

  // output projection: 128x320 tile -> 32x8 = 256 blocks = full machine
  gemm_t<128, 320, true><<<256, 512, 0, stream>>>(attn, woT, out + 2 * (size_t)T_TOK * NKV * HD,
                                                  2048, 2048, 2048, DM, 32);
}

// Round 12
// 251.487 us; speedup vs baseline: 1.8378x; 1.0455x over previous
//
#include <hip/hip_runtime.h>
#include <stdint.h>

// Problem constants (Gemma3 attention block)
#define T_TOK 4096
#define DM    2560
#define NQ    8
#define NKV   4
#define HD    256
#define WIN   1024

using bf16x8 = __attribute__((ext_vector_type(8))) short;
using f32x4  = __attribute__((ext_vector_type(4))) float;
typedef unsigned short u16;

__device__ __forceinline__ u16 f2bf(float x) {
  union { float f; uint32_t u; } v; v.f = x;
  uint32_t u = v.u;
  return (u16)((u + 0x7fffu + ((u >> 16) & 1u)) >> 16);  // RNE
}
__device__ __forceinline__ float bf2f(u16 b) {
  union { uint32_t u; float f; } v; v.u = ((uint32_t)b) << 16;
  return v.f;
}

// async global->LDS, 16B per lane. LDS dest is wave-uniform base; HW adds lane*16.
__device__ __forceinline__ void async_cp16(const void* g, void* lds) {
  __builtin_amdgcn_global_load_lds(
      (const __attribute__((address_space(1))) uint32_t*)(uintptr_t)g,
      (__attribute__((address_space(3))) uint32_t*)(uint32_t)(uintptr_t)lds,
      16, 0, 0);
}

// ---------------------------------------------------------------------------
// f32 -> bf16 elementwise convert (vectorized float4 loads)
__global__ __launch_bounds__(256) void convert_f32_bf16(
    const float* __restrict__ in, u16* __restrict__ out, int n)
{
  for (int i = (blockIdx.x * 256 + threadIdx.x) * 4; i < n; i += gridDim.x * 256 * 4) {
    float4 v = *(const float4*)(in + i);
    ushort4 o;
    o.x = f2bf(v.x); o.y = f2bf(v.y); o.z = f2bf(v.z); o.w = f2bf(v.w);
    *(ushort4*)(out + i) = o;
  }
}

// ---------------------------------------------------------------------------
// Tiled transpose + convert: in f32 (R x C) row-major -> out bf16 (C x R)
__global__ __launch_bounds__(256) void transpose_f32_bf16(
    const float* __restrict__ in, u16* __restrict__ out, int R, int C)
{
  __shared__ u16 tile[64][65];
  const int r0 = blockIdx.y * 64, c0 = blockIdx.x * 64;
  const int tr = threadIdx.x >> 6, tc = threadIdx.x & 63;
  #pragma unroll
  for (int i = 0; i < 16; ++i) {
    int r = tr + i * 4;
    tile[r][tc] = f2bf(in[(size_t)(r0 + r) * C + c0 + tc]);
  }
  __syncthreads();
  #pragma unroll
  for (int i = 0; i < 16; ++i) {
    int c = tr + i * 4;
    out[(size_t)(c0 + c) * R + r0 + tc] = tile[tc][c];
  }
}

// ---------------------------------------------------------------------------
// 256x256 bf16 GEMM, phase-interleaved progressive staging.
// C(MxN) = A(MxK) * B^T. 8 waves (2Mx4N), BK=64, LDS 128 KiB (2 buf).
// Per K-tile: 4 quadrant-phases. Staging of tile t+2 is spread into the
// CURRENT buffer as regions die (B after P0 reads; A-halves after P1/P3),
// proven disjoint from all remaining reads. vmcnt(8)+barrier once per tile.
template<bool F32OUT>
__global__ __launch_bounds__(512, 1) void gemm256p(
    const u16* __restrict__ A, const u16* __restrict__ B, void* __restrict__ Cv,
    int Kd, int lda, int ldb, int ldc)
{
  __shared__ __align__(16) u16 lds[2][2][256 * 64];  // [buf][A|B] 128 KiB
  const int tid = threadIdx.x;
  const int wave = tid >> 6, lane = tid & 63;
  const int lg = lane >> 4, lc = lane & 15;
  const int wr = wave >> 2, wc = wave & 3;  // 2 x 4 wave grid
  // XCD swizzle (grid 256, %8==0 -> bijective)
  const int nwg = gridDim.x, bid = blockIdx.x;
  const int nid = (bid & 7) * (nwg >> 3) + (bid >> 3);
  const int m0 = (nid & 15) * 256, n0 = (nid >> 4) * 256;
  const int NT = Kd >> 6;

  const int srow = tid >> 3;
  const int scol = ((tid & 7) * 16) ^ ((srow & 7) << 4);  // pre-swizzled source col
  const u16* Ag = A + (size_t)(m0 + srow) * lda + (scol >> 1);
  const u16* Bg = B + (size_t)(n0 + srow) * ldb + (scol >> 1);

  // B region: 4 issues (rows 0-256). A region: li = row/64; P1 stages li0,li2;
  // P3 stages li1,li3.
  #define STAGE_B4(BUF, KT) do {                                              \
    const int kc_ = (KT) * 64;                                                \
    _Pragma("unroll")                                                         \
    for (int li = 0; li < 4; ++li)                                            \
      async_cp16(Bg + (size_t)(li * 64) * ldb + kc_,                          \
                 (char*)&lds[BUF][1][0] + li * 8192 + wave * 1024);           \
  } while (0)
  #define STAGE_A2(BUF, KT, H) do {                                           \
    const int kc_ = (KT) * 64;                                                \
    async_cp16(Ag + (size_t)((H) * 64) * lda + kc_,                           \
               (char*)&lds[BUF][0][0] + (H) * 8192 + wave * 1024);            \
    async_cp16(Ag + (size_t)((H) * 64 + 128) * lda + kc_,                     \
               (char*)&lds[BUF][0][0] + ((H) + 2) * 8192 + wave * 1024);      \
  } while (0)

  #define LOAD_AF(P) do {                                                     \
    _Pragma("unroll")                                                         \
    for (int im = 0; im < 2; ++im)                                            \
      _Pragma("unroll")                                                       \
      for (int k2 = 0; k2 < 2; ++k2) {                                        \
        const int row = wr * 128 + ((P) * 2 + im) * 16 + lc;                  \
        const int cb = k2 * 64 + lg * 16;                                     \
        af[im][k2] = *(const bf16x8*)(Ab + row * 128 + (cb ^ ((row & 7) << 4))); \
      }                                                                       \
  } while (0)
  #define MFMA_Q(P) do {                                                      \
    __builtin_amdgcn_s_setprio(1);                                            \
    _Pragma("unroll")                                                         \
    for (int im = 0; im < 2; ++im)                                            \
      _Pragma("unroll")                                                       \
      for (int j = 0; j < 4; ++j)                                             \
        _Pragma("unroll")                                                     \
        for (int k2 = 0; k2 < 2; ++k2)                                        \
          acc[(P) * 2 + im][j] = __builtin_amdgcn_mfma_f32_16x16x32_bf16(     \
              af[im][k2], bfr[j][k2], acc[(P) * 2 + im][j], 0, 0, 0);         \
    __builtin_amdgcn_s_setprio(0);                                            \
  } while (0)
  #define LGKM0_BAR() do {                                                    \
    asm volatile("s_waitcnt lgkmcnt(0)" ::: "memory");                        \
    __builtin_amdgcn_s_barrier();                                             \
    __builtin_amdgcn_sched_barrier(0);                                        \
  } while (0)

  const f32x4 zf = {0.f, 0.f, 0.f, 0.f};
  f32x4 acc[8][4];
  #pragma unroll
  for (int i = 0; i < 8; ++i)
    #pragma unroll
    for (int j = 0; j < 4; ++j) acc[i][j] = zf;

  // prologue: full tiles 0 -> buf0, 1 -> buf1; wait tile 0 (8 newest in flight)
  STAGE_B4(0, 0); STAGE_A2(0, 0, 0); STAGE_A2(0, 0, 1);
  STAGE_B4(1, 1); STAGE_A2(1, 1, 0); STAGE_A2(1, 1, 1);
  asm volatile("s_waitcnt vmcnt(8)" ::: "memory");
  __builtin_amdgcn_s_barrier();
  __builtin_amdgcn_sched_barrier(0);

  for (int t = 0; t < NT; ++t) {
    const int cur = t & 1;
    const char* Ab = (const char*)&lds[cur][0][0];
    const char* Bb = (const char*)&lds[cur][1][0];
    int nk = t + 2; if (nk > NT - 1) nk = NT - 1;  // clamped tail: dead-buffer writes only

    bf16x8 bfr[4][2], af[2][2];
    // ---- P0: all B-frags + q0 A-frags; then B region is dead -> stage B(t+2)
    #pragma unroll
    for (int j = 0; j < 4; ++j)
      #pragma unroll
      for (int k2 = 0; k2 < 2; ++k2) {
        const int row = wc * 64 + j * 16 + lc;
        const int cb = k2 * 64 + lg * 16;
        bfr[j][k2] = *(const bf16x8*)(Bb + row * 128 + (cb ^ ((row & 7) << 4)));
      }
    LOAD_AF(0);
    LGKM0_BAR();
    STAGE_B4(cur, nk);
    MFMA_Q(0);
    // ---- P1: q1 A-frags; A rows {0-64,128-192} dead -> stage
    LOAD_AF(1);
    LGKM0_BAR();
    STAGE_A2(cur, nk, 0);
    MFMA_Q(1);
    // ---- P2: no staging, no barrier (reads disjoint from staged regions)
    LOAD_AF(2);
    MFMA_Q(2);
    // ---- P3: q3 A-frags; A rows {64-128,192-256} dead -> stage
    LOAD_AF(3);
    LGKM0_BAR();
    STAGE_A2(cur, nk, 1);
    MFMA_Q(3);
    // ---- tile end: t+1's 8 loads landed (t+2's 8 newest stay in flight)
    asm volatile("s_waitcnt vmcnt(8)" ::: "memory");
    __builtin_amdgcn_s_barrier();
    __builtin_amdgcn_sched_barrier(0);
  }
  #undef STAGE_B4
  #undef STAGE_A2
  #undef LOAD_AF
  #undef MFMA_Q
  #undef LGKM0_BAR

  #pragma unroll
  for (int i = 0; i < 8; ++i)
    #pragma unroll
    for (int j = 0; j < 4; ++j)
      #pragma unroll
      for (int r = 0; r < 4; ++r) {
        const int row = m0 + wr * 128 + i * 16 + lg * 4 + r;
        const int col = n0 + wc * 64 + j * 16 + lc;
        if (F32OUT) ((float*)Cv)[(size_t)row * ldc + col] = acc[i][j][r];
        else        ((u16*)Cv)[(size_t)row * ldc + col] = f2bf(acc[i][j][r]);
      }
}

// ---------------------------------------------------------------------------
// BMxBN bf16 GEMM, counted-vmcnt double-buffered pipeline (verified schedule;
// used for the o-projection). 8 waves (2Mx4N), BK=64. 1D grid, XCD swizzle.
template<int BM, int BN, bool F32OUT>
__global__ __launch_bounds__(512, 2) void gemm_t(
    const u16* __restrict__ A, const u16* __restrict__ B, void* __restrict__ Cv,
    int Kd, int lda, int ldb, int ldc, int MT)
{
  constexpr int MF = BM / 32;
  constexpr int NF = BN / 64;
  constexpr int ISS = (BM + BN) / 64;
  constexpr int AISS = BM / 64;
  __shared__ __align__(16) u16 lds[2][(BM + BN) * 64];
  const int tid = threadIdx.x;
  const int wave = tid >> 6, lane = tid & 63;
  const int lg = lane >> 4, lc = lane & 15;
  const int wr = wave >> 2, wc = wave & 3;
  const int nwg = gridDim.x, bid = blockIdx.x;
  const int nid = (bid & 7) * (nwg >> 3) + (bid >> 3);
  const int m0 = (nid % MT) * BM, n0 = (nid / MT) * BN;
  const int NT = Kd >> 6;

  const int srow = tid >> 3;
  const int scol = ((tid & 7) * 16) ^ ((srow & 7) << 4);
  const u16* Ag = A + (size_t)(m0 + srow) * lda + (scol >> 1);
  const u16* Bg = B + (size_t)(n0 + srow) * ldb + (scol >> 1);
  char* lds0 = (char*)&lds[0][0];
  char* lds1 = (char*)&lds[1][0];

  #define STAGE_T(LD, KT) do {                                              \
    const int kc_ = (KT) * 64;                                              \
    _Pragma("unroll")                                                       \
    for (int li = 0; li < ISS; ++li) {                                      \
      if (li < AISS)                                                        \
        async_cp16(Ag + (size_t)(li * 64) * lda + kc_,                      \
                   (LD) + li * 8192 + wave * 1024);                         \
      else                                                                  \
        async_cp16(Bg + (size_t)((li - AISS) * 64) * ldb + kc_,             \
                   (LD) + li * 8192 + wave * 1024);                         \
    }                                                                       \
  } while (0)

  #define WAIT_ISS() do {                                                   \
    if (ISS == 8) asm volatile("s_waitcnt vmcnt(8)" ::: "memory");          \
    else          asm volatile("s_waitcnt vmcnt(7)" ::: "memory");          \
  } while (0)

  const f32x4 zf = {0.f, 0.f, 0.f, 0.f};
  f32x4 acc[MF][NF];
  #pragma unroll
  for (int i = 0; i < MF; ++i)
    #pragma unroll
    for (int j = 0; j < NF; ++j) acc[i][j] = zf;

  STAGE_T(lds0, 0);
  STAGE_T(lds1, 1);
  WAIT_ISS();
  __builtin_amdgcn_s_barrier();
  __builtin_amdgcn_sched_barrier(0);

  for (int t = 0; t < NT; ++t) {
    const int cur = t & 1;
    const char* Ab = cur ? lds1 : lds0;
    const char* Bb = Ab + BM * 128;

    bf16x8 bf[NF][2];
    #pragma unroll
    for (int j = 0; j < NF; ++j)
      #pragma unroll
      for (int k2 = 0; k2 < 2; ++k2) {
        const int row = wc * (BN / 4) + j * 16 + lc;
        const int cb = k2 * 64 + lg * 16;
        bf[j][k2] = *(const bf16x8*)(Bb + row * 128 + (cb ^ ((row & 7) << 4)));
      }

    #pragma unroll
    for (int p = 0; p < MF / 2; ++p) {
      bf16x8 af[2][2];
      #pragma unroll
      for (int im = 0; im < 2; ++im)
        #pragma unroll
        for (int k2 = 0; k2 < 2; ++k2) {
          const int row = wr * (BM / 2) + (p * 2 + im) * 16 + lc;
          const int cb = k2 * 64 + lg * 16;
          af[im][k2] = *(const bf16x8*)(Ab + row * 128 + (cb ^ ((row & 7) << 4)));
        }
      __builtin_amdgcn_s_setprio(1);
      #pragma unroll
      for (int im = 0; im < 2; ++im)
        #pragma unroll
        for (int j = 0; j < NF; ++j)
          #pragma unroll
          for (int k2 = 0; k2 < 2; ++k2)
            acc[p * 2 + im][j] = __builtin_amdgcn_mfma_f32_16x16x32_bf16(
                af[im][k2], bf[j][k2], acc[p * 2 + im][j], 0, 0, 0);
      __builtin_amdgcn_s_setprio(0);
    }

    __builtin_amdgcn_s_barrier();
    __builtin_amdgcn_sched_barrier(0);
    int nk = t + 2; if (nk > NT - 1) nk = NT - 1;
    if (cur == 0) { STAGE_T(lds0, nk); } else { STAGE_T(lds1, nk); }
    WAIT_ISS();
    __builtin_amdgcn_s_barrier();
    __builtin_amdgcn_sched_barrier(0);
  }
  #undef STAGE_T
  #undef WAIT_ISS

  #pragma unroll
  for (int i = 0; i < MF; ++i)
    #pragma unroll
    for (int j = 0; j < NF; ++j)
      #pragma unroll
      for (int r = 0; r < 4; ++r) {
        const int row = m0 + wr * (BM / 2) + i * 16 + lg * 4 + r;
        const int col = n0 + wc * (BN / 4) + j * 16 + lc;
        if (F32OUT) ((float*)Cv)[(size_t)row * ldc + col] = acc[i][j][r];
        else        ((u16*)Cv)[(size_t)row * ldc + col] = f2bf(acc[i][j][r]);
      }
}

// ---------------------------------------------------------------------------
// Fused RMSNorm + query-scale + RoPE. Reads qkv (T x 4096 bf16):
// cols [0,2048) = q (n-major), [2048,3072) = k, [3072,4096) = v.
__global__ __launch_bounds__(256) void fuse_norm_rope(
    const u16* __restrict__ qkv, const float* __restrict__ qnw, const float* __restrict__ knw,
    const int* __restrict__ pos, u16* __restrict__ qb, u16* __restrict__ kb,
    u16* __restrict__ vb, float* __restrict__ kvout)
{
  const int t = blockIdx.x;
  const int wave = threadIdx.x >> 6, lane = threadIdx.x & 63;
  const float p = (float)pos[t];
  const float kf = 0.10381025296523007f;  // log2(10000)/128
  float s0, c0, s1, c1;
  sincosf(p * exp2f(-(float)lane * kf), &s0, &c0);
  sincosf(p * exp2f(-(float)(lane + 64) * kf), &s1, &c1);
  const u16* row = qkv + (size_t)t * 4096;

  for (int pp = 0; pp < 4; ++pp) {
    const int hr = pp * 4 + wave;  // 0..7 q, 8..11 k, 12..15 v
    if (hr >= 12) {
      const int kk = hr - 12;
      const u16* src = row + 3072 + kk * 256;
      float* dstf = kvout + (size_t)T_TOK * NKV * HD + ((size_t)t * NKV + kk) * HD;
      u16*   dstb = vb + ((size_t)t * NKV + kk) * HD;
      #pragma unroll
      for (int q4 = 0; q4 < 4; ++q4) {
        const u16 s = src[lane + q4 * 64];
        dstf[lane + q4 * 64] = bf2f(s);
        dstb[lane + q4 * 64] = s;
      }
    } else {
      const bool isq = hr < 8;
      const int cb = isq ? hr * 256 : 2048 + (hr - 8) * 256;
      float v0 = bf2f(row[cb + lane]);
      float v1 = bf2f(row[cb + lane + 64]);
      float v2 = bf2f(row[cb + lane + 128]);
      float v3 = bf2f(row[cb + lane + 192]);
      float ss = v0 * v0 + v1 * v1 + v2 * v2 + v3 * v3;
      #pragma unroll
      for (int off = 1; off < 64; off <<= 1) ss += __shfl_xor(ss, off);
      float sc = rsqrtf(ss * (1.0f / 256.0f) + 1e-6f);
      if (isq) sc *= 0.0625f;  // QUERY_PRE_ATTN_SCALAR^-0.5
      const float* wn = isq ? qnw : knw;
      v0 *= sc * wn[lane];
      v1 *= sc * wn[lane + 64];
      v2 *= sc * wn[lane + 128];
      v3 *= sc * wn[lane + 192];
      const float n0 = v0 * c0 - v2 * s0;
      const float n2 = v2 * c0 + v0 * s0;
      const float n1 = v1 * c1 - v3 * s1;
      const float n3 = v3 * c1 + v1 * s1;
      if (isq) {
        u16* dst = qb + (size_t)t * 2048 + hr * 256;
        dst[lane]       = f2bf(n0);
        dst[lane + 64]  = f2bf(n1);
        dst[lane + 128] = f2bf(n2);
        dst[lane + 192] = f2bf(n3);
      } else {
        const int kk = hr - 8;
        float* dstf = kvout + ((size_t)t * NKV + kk) * HD;
        dstf[lane]       = n0;
        dstf[lane + 64]  = n1;
        dstf[lane + 128] = n2;
        dstf[lane + 192] = n3;
        u16* dstb = kb + ((size_t)t * NKV + kk) * HD;
        dstb[lane]       = f2bf(n0);
        dstb[lane + 64]  = f2bf(n1);
        dstb[lane + 128] = f2bf(n2);
        dstb[lane + 192] = f2bf(n3);
      }
    }
  }
}

// ---------------------------------------------------------------------------
// Per-head V transpose: vb (T x NKV x HD bf16) -> vt (NKV x HD x T bf16)
__global__ __launch_bounds__(256) void transpose_v(
    const u16* __restrict__ vc, u16* __restrict__ vt)
{
  __shared__ u16 tile[64][65];
  const int kk = blockIdx.z;
  const int t0 = blockIdx.y * 64, h0 = blockIdx.x * 64;
  const int tr = threadIdx.x >> 6, tc = threadIdx.x & 63;
  #pragma unroll
  for (int i = 0; i < 16; ++i) {
    int tt = tr + i * 4;
    tile[tt][tc] = vc[((size_t)(t0 + tt) * NKV + kk) * HD + h0 + tc];
  }
  __syncthreads();
  #pragma unroll
  for (int i = 0; i < 16; ++i) {
    int h = tr + i * 4;
    vt[(size_t)kk * HD * T_TOK + (size_t)(h0 + h) * T_TOK + t0 + tc] = tile[tc][h];
  }
}

// ---------------------------------------------------------------------------
// Flash attention v5: 2 q-heads per block (one kv head), double-buffered
// global_load_lds K/V staging, wave-local softmax, per-wave private P slice,
// one barrier per tile. LDS 144 KB -> 1 block/CU, 8 waves.
__global__ __launch_bounds__(512, 1) void attn_kernel(
    const u16* __restrict__ qb, const u16* __restrict__ kc,
    const u16* __restrict__ vt, u16* __restrict__ ob)
{
  __shared__ __align__(16) u16 Ks[2][64 * 256];    // [buf][key][d] swz
  __shared__ __align__(16) u16 Vts[2][256 * 64];   // [buf][d][key] swz
  __shared__ __align__(16) u16 Ps[8][16 * 64];     // per-wave [qrow][key] swz

  const int kk = blockIdx.y;             // kv head
  const int t0 = blockIdx.x * 64;
  const int tid = threadIdx.x;
  const int wave = tid >> 6, lane = tid & 63;
  const int lg = lane >> 4, lc = lane & 15;
  const int hq = kk * 2 + (wave >> 2);   // q head for this wave
  const int wrow = (wave & 3) * 16;      // q-row base within 64-row block
  const int lswz = (lc & 7) << 4;
  const f32x4 zf = {0.f, 0.f, 0.f, 0.f};

  // staging geometry (512 threads): K 4 issues x 16 rows, V 4 issues x 64 rows
  const int lrowK = tid >> 5;                        // 0..15
  const int scolK = ((tid & 31) * 16) ^ ((lrowK & 7) << 4);
  const int lrowV = tid >> 3;                        // 0..63
  const int scolV = ((tid & 7) * 16) ^ ((lrowV & 7) << 4);

  #define STAGEKV(KT, BUF) do {                                                \
    const int kb_ = (KT) * 64;                                                 \
    const u16* kp_ = kc + (size_t)(kb_ + lrowK) * (NKV * HD) + kk * HD + (scolK >> 1); \
    _Pragma("unroll")                                                          \
    for (int is = 0; is < 4; ++is)                                             \
      async_cp16(kp_ + (size_t)(is * 16) * (NKV * HD),                         \
                 (char*)&Ks[BUF][0] + is * 8192 + wave * 1024);                \
    const u16* vp_ = vt + (size_t)kk * (HD * T_TOK) + (size_t)lrowV * T_TOK + kb_ + (scolV >> 1); \
    _Pragma("unroll")                                                          \
    for (int is = 0; is < 4; ++is)                                             \
      async_cp16(vp_ + (size_t)(is * 64) * T_TOK,                              \
                 (char*)&Vts[BUF][0] + is * 8192 + wave * 1024);               \
  } while (0)

  // Q fragments straight from global (rows t0+wrow+lc of head hq)
  bf16x8 qf[8];
  {
    const u16* qp = qb + (size_t)(t0 + wrow + lc) * 2048 + hq * 256 + lg * 8;
    #pragma unroll
    for (int ks = 0; ks < 8; ++ks) qf[ks] = *(const bf16x8*)(qp + ks * 32);
  }

  f32x4 o_acc[16];
  #pragma unroll
  for (int j = 0; j < 16; ++j) o_acc[j] = zf;
  float m_r[4], l_r[4];
  #pragma unroll
  for (int r = 0; r < 4; ++r) { m_r[r] = -1e30f; l_r[r] = 0.f; }

  const int mtile = t0 >> 6;
  const int ktf = (mtile >= 16) ? (mtile - 16) : 0;

  // prologue: stage first tile into buf 0 (drain via syncthreads)
  STAGEKV(ktf, 0);
  __syncthreads();

  int cur = 0;
  for (int kt = ktf; kt <= mtile; ++kt) {
    const int kb = kt * 64;
    // issue next tile's staging into the other buffer (lands under compute)
    if (kt < mtile) STAGEKV(kt + 1, cur ^ 1);

    const u16* Kb = &Ks[cur][0];
    const u16* Vb = &Vts[cur][0];

    // ---- S = Q K^T : this wave's 16 rows x 64 keys
    f32x4 sf[4];
    #pragma unroll
    for (int j = 0; j < 4; ++j) sf[j] = zf;
    __builtin_amdgcn_s_setprio(1);
    #pragma unroll
    for (int ks = 0; ks < 8; ++ks)
      #pragma unroll
      for (int j = 0; j < 4; ++j) {
        const int row = j * 16 + lc;
        bf16x8 kf = *(const bf16x8*)((const char*)Kb + ((row * 512 + ks * 64 + lg * 16) ^ lswz));
        sf[j] = __builtin_amdgcn_mfma_f32_16x16x32_bf16(qf[ks], kf, sf[j], 0, 0, 0);
      }
    __builtin_amdgcn_s_setprio(0);

    // ---- mask (skip fully-interior tiles)
    const bool interior = (kb >= t0 - 960) && (kb <= t0 - 64);
    if (!interior) {
      #pragma unroll
      for (int j = 0; j < 4; ++j) {
        const int gcol = kb + j * 16 + lc;
        #pragma unroll
        for (int r = 0; r < 4; ++r) {
          const int grow = t0 + wrow + lg * 4 + r;
          if ((unsigned)(grow - gcol) >= WIN) sf[j][r] = -1e30f;
        }
      }
    }

    // ---- wave-local online softmax (rows lg*4+r, reduce over 16 lc lanes)
    float a_r[4];
    #pragma unroll
    for (int r = 0; r < 4; ++r) {
      float v = fmaxf(fmaxf(sf[0][r], sf[1][r]), fmaxf(sf[2][r], sf[3][r]));
      v = fmaxf(v, __shfl_xor(v, 1));
      v = fmaxf(v, __shfl_xor(v, 2));
      v = fmaxf(v, __shfl_xor(v, 4));
      v = fmaxf(v, __shfl_xor(v, 8));
      const float mn = fmaxf(m_r[r], v);
      a_r[r] = __expf(m_r[r] - mn);
      m_r[r] = mn;
    }

    // ---- P = exp(S-m) -> own LDS slice; row sums; l update
    char* myP = (char*)&Ps[wave][0];
    #pragma unroll
    for (int r = 0; r < 4; ++r) {
      const int row = lg * 4 + r;
      const int rsw = (row & 7) << 4;
      float su = 0.f;
      #pragma unroll
      for (int j = 0; j < 4; ++j) {
        const float p = __expf(sf[j][r] - m_r[r]);
        su += p;
        *(u16*)(myP + ((row * 128 + (j * 16 + lc) * 2) ^ rsw)) = f2bf(p);
      }
      su += __shfl_xor(su, 1);
      su += __shfl_xor(su, 2);
      su += __shfl_xor(su, 4);
      su += __shfl_xor(su, 8);
      l_r[r] = l_r[r] * a_r[r] + su;
    }

    // ---- rescale O
    #pragma unroll
    for (int j = 0; j < 16; ++j) {
      o_acc[j][0] *= a_r[0];
      o_acc[j][1] *= a_r[1];
      o_acc[j][2] *= a_r[2];
      o_acc[j][3] *= a_r[3];
    }

    // ---- O += P * V (P read is wave-private: lgkmcnt only, no barrier)
    bf16x8 pa[2];
    #pragma unroll
    for (int ks = 0; ks < 2; ++ks)
      pa[ks] = *(const bf16x8*)(myP + ((lc * 128 + ks * 64 + lg * 16) ^ lswz));
    __builtin_amdgcn_s_setprio(1);
    #pragma unroll
    for (int ks = 0; ks < 2; ++ks)
      #pragma unroll
      for (int j = 0; j < 16; ++j) {
        const int row = j * 16 + lc;
        bf16x8 vf = *(const bf16x8*)((const char*)Vb + ((row * 128 + ks * 64 + lg * 16) ^ lswz));
        o_acc[j] = __builtin_amdgcn_mfma_f32_16x16x32_bf16(pa[ks], vf, o_acc[j], 0, 0, 0);
      }
    __builtin_amdgcn_s_setprio(0);

    // single barrier: releases buf[cur] for restaging AND (implicit vmcnt
    // drain) guarantees tile kt+1 landed in buf[cur^1] for all waves
    __syncthreads();
    cur ^= 1;
  }
  #undef STAGEKV

  // ---- epilogue: O / l -> attn buffer (T x 2048 bf16)
  #pragma unroll
  for (int r = 0; r < 4; ++r) {
    const float li = 1.f / l_r[r];
    const size_t rowb = (size_t)(t0 + wrow + lg * 4 + r) * 2048 + hq * 256 + lc;
    #pragma unroll
    for (int j = 0; j < 16; ++j)
      ob[rowb + j * 16] = f2bf(o_acc[j][r] * li);
  }
}

// ---------------------------------------------------------------------------
extern "C" void kernel_launch(void* const* d_in, const int* in_sizes, int n_in,
                              void* d_out, int out_size, void* d_ws, size_t ws_size,
                              hipStream_t stream)
{
  (void)in_sizes; (void)n_in; (void)out_size; (void)ws_size;
  const float* x   = (const float*)d_in[0];
  const float* wq  = (const float*)d_in[1];
  const float* wk  = (const float*)d_in[2];
  const float* wv  = (const float*)d_in[3];
  const float* wo  = (const float*)d_in[4];
  const float* qnw = (const float*)d_in[5];
  const float* knw = (const float*)d_in[6];
  const int*   pos = (const int*)d_in[7];
  float* out = (float*)d_out;  // f32: [2*T*NKV*HD kv cache][T*DM o]

  // workspace layout (peak 86 MB), lifetime-aliased
  char* ws = (char*)d_ws;
  u16* woT   = (u16*)(ws);                    // 2560x2048 bf16 (10.5 MB), live to end
  u16* xb    = (u16*)(ws + 10485760);         // T x DM bf16 (21.0 MB)
  u16* wqkvT = (u16*)(ws + 31457280);         // 4096 x DM bf16 (21.0 MB)
  u16* qkv   = (u16*)(ws + 52428800);         // T x 4096 bf16 (33.6 MB)
  u16* q_b   = xb;                            // alias: xb dead after gemm1 (16.8 MB)
  u16* kb    = wqkvT;                         // alias: wqkvT dead after gemm1 (8.4 MB)
  u16* vb    = (u16*)(ws + 31457280 + 8388608); // (8.4 MB, still inside wqkvT)
  u16* vtb   = qkv;                           // alias: qkv dead after fuse (8.4 MB)
  u16* attn  = (u16*)(ws + 52428800 + 8388608); // (16.8 MB, inside qkv region)

  convert_f32_bf16<<<2048, 256, 0, stream>>>(x, xb, T_TOK * DM);
  transpose_f32_bf16<<<dim3(32, 40), 256, 0, stream>>>(wq, wqkvT, DM, 2048);
  transpose_f32_bf16<<<dim3(16, 40), 256, 0, stream>>>(wk, wqkvT + 2048 * DM, DM, 1024);
  transpose_f32_bf16<<<dim3(16, 40), 256, 0, stream>>>(wv, wqkvT + 3072 * DM, DM, 1024);
  transpose_f32_bf16<<<dim3(40, 32), 256, 0, stream>>>(wo, woT, 2048, DM);

  // QKV projection: 256x256 tile, phase-interleaved schedule, 256 blocks
  gemm256p<false><<<256, 512, 0, stream>>>(xb, wqkvT, qkv, DM, DM, DM, 4096);

  // RMSNorm + scale + RoPE; k/v f32 into kv cache (d_out) + bf16 copies
  fuse_norm_rope<<<T_TOK, 256, 0, stream>>>(qkv, qnw, knw, pos, q_b, kb, vb, out);

  // V^T per head for PV MFMA B-operand
  transpose_v<<<dim3(4, 64, 4), 256, 0, stream>>>(vb, vtb);

  // flash attention: 64-row q-block x kv-head (2 q heads) -> attn (T x 2048)
  attn_kernel<<<dim3(64, 4), 512, 0, stream>>>(q_b, kb, vtb, attn);

  // output projection: 128x320 tile -> 32x8 = 256 blocks = full machine
  gemm_t<128, 320, true><<<256, 512, 0, stream>>>(attn, woT, out + 2 * (size_t)T_TOK * NKV * HD,
                                                  2048, 2048, 2048, DM, 32);
}

// Round 13
// 250.328 us; speedup vs baseline: 1.8463x; 1.0046x over previous
//
#include <hip/hip_runtime.h>
#include <stdint.h>

// Problem constants (Gemma3 attention block)
#define T_TOK 4096
#define DM    2560
#define NQ    8
#define NKV   4
#define HD    256
#define WIN   1024

using bf16x8 = __attribute__((ext_vector_type(8))) short;
using f32x4  = __attribute__((ext_vector_type(4))) float;
typedef unsigned short u16;

__device__ __forceinline__ u16 f2bf(float x) {
  union { float f; uint32_t u; } v; v.f = x;
  uint32_t u = v.u;
  return (u16)((u + 0x7fffu + ((u >> 16) & 1u)) >> 16);  // RNE
}
__device__ __forceinline__ float bf2f(u16 b) {
  union { uint32_t u; float f; } v; v.u = ((uint32_t)b) << 16;
  return v.f;
}

// async global->LDS, 16B per lane. LDS dest is wave-uniform base; HW adds lane*16.
__device__ __forceinline__ void async_cp16(const void* g, void* lds) {
  __builtin_amdgcn_global_load_lds(
      (const __attribute__((address_space(1))) uint32_t*)(uintptr_t)g,
      (__attribute__((address_space(3))) uint32_t*)(uint32_t)(uintptr_t)lds,
      16, 0, 0);
}

// ---------------------------------------------------------------------------
// f32 -> bf16 elementwise convert (8 elems/thread, 16B stores)
__global__ __launch_bounds__(256) void convert_f32_bf16(
    const float* __restrict__ in, u16* __restrict__ out, int n)
{
  for (int i = (blockIdx.x * 256 + threadIdx.x) * 8; i < n; i += gridDim.x * 256 * 8) {
    float4 a = *(const float4*)(in + i);
    float4 b = *(const float4*)(in + i + 4);
    bf16x8 o;
    o[0] = (short)f2bf(a.x); o[1] = (short)f2bf(a.y);
    o[2] = (short)f2bf(a.z); o[3] = (short)f2bf(a.w);
    o[4] = (short)f2bf(b.x); o[5] = (short)f2bf(b.y);
    o[6] = (short)f2bf(b.z); o[7] = (short)f2bf(b.w);
    *(bf16x8*)(out + i) = o;
  }
}

// ---------------------------------------------------------------------------
// Tiled transpose + convert: in f32 (R x C) row-major -> out bf16 (C x R).
// 16B vectorized output stores (padded LDS tile, 144B row stride).
__global__ __launch_bounds__(256) void transpose_f32_bf16(
    const float* __restrict__ in, u16* __restrict__ out, int R, int C)
{
  __shared__ u16 tile[64][72];
  const int r0 = blockIdx.y * 64, c0 = blockIdx.x * 64;
  const int tr = threadIdx.x >> 6, tc = threadIdx.x & 63;
  #pragma unroll
  for (int i = 0; i < 16; ++i) {
    int r = tr + i * 4;
    tile[r][tc] = f2bf(in[(size_t)(r0 + r) * C + c0 + tc]);
  }
  __syncthreads();
  const int oc = threadIdx.x >> 3, ch = threadIdx.x & 7;
  #pragma unroll
  for (int h = 0; h < 2; ++h) {
    const int c = oc + h * 32;  // output row = c0 + c
    bf16x8 v;
    #pragma unroll
    for (int j = 0; j < 8; ++j) v[j] = (short)tile[ch * 8 + j][c];
    *(bf16x8*)(out + (size_t)(c0 + c) * R + r0 + ch * 8) = v;
  }
}

// ---------------------------------------------------------------------------
// 256x256 bf16 GEMM, phase-interleaved progressive staging (QKV projection).
template<bool F32OUT>
__global__ __launch_bounds__(512, 1) void gemm256p(
    const u16* __restrict__ A, const u16* __restrict__ B, void* __restrict__ Cv,
    int Kd, int lda, int ldb, int ldc)
{
  __shared__ __align__(16) u16 lds[2][2][256 * 64];  // [buf][A|B] 128 KiB
  const int tid = threadIdx.x;
  const int wave = tid >> 6, lane = tid & 63;
  const int lg = lane >> 4, lc = lane & 15;
  const int wr = wave >> 2, wc = wave & 3;  // 2 x 4 wave grid
  const int nwg = gridDim.x, bid = blockIdx.x;
  const int nid = (bid & 7) * (nwg >> 3) + (bid >> 3);
  const int m0 = (nid & 15) * 256, n0 = (nid >> 4) * 256;
  const int NT = Kd >> 6;

  const int srow = tid >> 3;
  const int scol = ((tid & 7) * 16) ^ ((srow & 7) << 4);
  const u16* Ag = A + (size_t)(m0 + srow) * lda + (scol >> 1);
  const u16* Bg = B + (size_t)(n0 + srow) * ldb + (scol >> 1);

  #define STAGE_B4(BUF, KT) do {                                              \
    const int kc_ = (KT) * 64;                                                \
    _Pragma("unroll")                                                         \
    for (int li = 0; li < 4; ++li)                                            \
      async_cp16(Bg + (size_t)(li * 64) * ldb + kc_,                          \
                 (char*)&lds[BUF][1][0] + li * 8192 + wave * 1024);           \
  } while (0)
  #define STAGE_A2(BUF, KT, H) do {                                           \
    const int kc_ = (KT) * 64;                                                \
    async_cp16(Ag + (size_t)((H) * 64) * lda + kc_,                           \
               (char*)&lds[BUF][0][0] + (H) * 8192 + wave * 1024);            \
    async_cp16(Ag + (size_t)((H) * 64 + 128) * lda + kc_,                     \
               (char*)&lds[BUF][0][0] + ((H) + 2) * 8192 + wave * 1024);      \
  } while (0)
  #define LOAD_AF(P) do {                                                     \
    _Pragma("unroll")                                                         \
    for (int im = 0; im < 2; ++im)                                            \
      _Pragma("unroll")                                                       \
      for (int k2 = 0; k2 < 2; ++k2) {                                        \
        const int row = wr * 128 + ((P) * 2 + im) * 16 + lc;                  \
        const int cb = k2 * 64 + lg * 16;                                     \
        af[im][k2] = *(const bf16x8*)(Ab + row * 128 + (cb ^ ((row & 7) << 4))); \
      }                                                                       \
  } while (0)
  #define MFMA_Q(P) do {                                                      \
    __builtin_amdgcn_s_setprio(1);                                            \
    _Pragma("unroll")                                                         \
    for (int im = 0; im < 2; ++im)                                            \
      _Pragma("unroll")                                                       \
      for (int j = 0; j < 4; ++j)                                             \
        _Pragma("unroll")                                                     \
        for (int k2 = 0; k2 < 2; ++k2)                                        \
          acc[(P) * 2 + im][j] = __builtin_amdgcn_mfma_f32_16x16x32_bf16(     \
              af[im][k2], bfr[j][k2], acc[(P) * 2 + im][j], 0, 0, 0);         \
    __builtin_amdgcn_s_setprio(0);                                            \
  } while (0)
  #define LGKM0_BAR() do {                                                    \
    asm volatile("s_waitcnt lgkmcnt(0)" ::: "memory");                        \
    __builtin_amdgcn_s_barrier();                                             \
    __builtin_amdgcn_sched_barrier(0);                                        \
  } while (0)

  const f32x4 zf = {0.f, 0.f, 0.f, 0.f};
  f32x4 acc[8][4];
  #pragma unroll
  for (int i = 0; i < 8; ++i)
    #pragma unroll
    for (int j = 0; j < 4; ++j) acc[i][j] = zf;

  STAGE_B4(0, 0); STAGE_A2(0, 0, 0); STAGE_A2(0, 0, 1);
  STAGE_B4(1, 1); STAGE_A2(1, 1, 0); STAGE_A2(1, 1, 1);
  asm volatile("s_waitcnt vmcnt(8)" ::: "memory");
  __builtin_amdgcn_s_barrier();
  __builtin_amdgcn_sched_barrier(0);

  for (int t = 0; t < NT; ++t) {
    const int cur = t & 1;
    const char* Ab = (const char*)&lds[cur][0][0];
    const char* Bb = (const char*)&lds[cur][1][0];
    int nk = t + 2; if (nk > NT - 1) nk = NT - 1;

    bf16x8 bfr[4][2], af[2][2];
    #pragma unroll
    for (int j = 0; j < 4; ++j)
      #pragma unroll
      for (int k2 = 0; k2 < 2; ++k2) {
        const int row = wc * 64 + j * 16 + lc;
        const int cb = k2 * 64 + lg * 16;
        bfr[j][k2] = *(const bf16x8*)(Bb + row * 128 + (cb ^ ((row & 7) << 4)));
      }
    LOAD_AF(0);
    LGKM0_BAR();
    STAGE_B4(cur, nk);
    MFMA_Q(0);
    LOAD_AF(1);
    LGKM0_BAR();
    STAGE_A2(cur, nk, 0);
    MFMA_Q(1);
    LOAD_AF(2);
    MFMA_Q(2);
    LOAD_AF(3);
    LGKM0_BAR();
    STAGE_A2(cur, nk, 1);
    MFMA_Q(3);
    asm volatile("s_waitcnt vmcnt(8)" ::: "memory");
    __builtin_amdgcn_s_barrier();
    __builtin_amdgcn_sched_barrier(0);
  }
  #undef STAGE_B4
  #undef STAGE_A2
  #undef LOAD_AF
  #undef MFMA_Q
  #undef LGKM0_BAR

  #pragma unroll
  for (int i = 0; i < 8; ++i)
    #pragma unroll
    for (int j = 0; j < 4; ++j)
      #pragma unroll
      for (int r = 0; r < 4; ++r) {
        const int row = m0 + wr * 128 + i * 16 + lg * 4 + r;
        const int col = n0 + wc * 64 + j * 16 + lc;
        if (F32OUT) ((float*)Cv)[(size_t)row * ldc + col] = acc[i][j][r];
        else        ((u16*)Cv)[(size_t)row * ldc + col] = f2bf(acc[i][j][r]);
      }
}

// ---------------------------------------------------------------------------
// 128x320 bf16 GEMM, same progressive schedule (o-projection).
// 8 waves 2Mx4N: per-wave 64x80 (MF=4 -> 2 q-phases, NF=5). ISS=7 (5 B + 2 A).
__global__ __launch_bounds__(512, 1) void gemm_p2(
    const u16* __restrict__ A, const u16* __restrict__ B, float* __restrict__ C,
    int Kd, int lda, int ldb, int ldc)
{
  __shared__ __align__(16) u16 lds[2][(128 + 320) * 64];  // 114688 B
  const int tid = threadIdx.x;
  const int wave = tid >> 6, lane = tid & 63;
  const int lg = lane >> 4, lc = lane & 15;
  const int wr = wave >> 2, wc = wave & 3;
  const int nwg = gridDim.x, bid = blockIdx.x;
  const int nid = (bid & 7) * (nwg >> 3) + (bid >> 3);
  const int m0 = (nid & 31) * 128, n0 = (nid >> 5) * 320;
  const int NT = Kd >> 6;

  const int srow = tid >> 3;
  const int scol = ((tid & 7) * 16) ^ ((srow & 7) << 4);
  const u16* Ag = A + (size_t)(m0 + srow) * lda + (scol >> 1);
  const u16* Bg = B + (size_t)(n0 + srow) * ldb + (scol >> 1);

  #define STAGE_B5(BUF, KT) do {                                              \
    const int kc_ = (KT) * 64;                                                \
    _Pragma("unroll")                                                         \
    for (int li = 0; li < 5; ++li)                                            \
      async_cp16(Bg + (size_t)(li * 64) * ldb + kc_,                          \
                 (char*)&lds[BUF][0] + 16384 + li * 8192 + wave * 1024);      \
  } while (0)
  #define STAGE_A2P(BUF, KT) do {                                             \
    const int kc_ = (KT) * 64;                                                \
    _Pragma("unroll")                                                         \
    for (int li = 0; li < 2; ++li)                                            \
      async_cp16(Ag + (size_t)(li * 64) * lda + kc_,                          \
                 (char*)&lds[BUF][0] + li * 8192 + wave * 1024);              \
  } while (0)
  #define LOAD_AF2(P) do {                                                    \
    _Pragma("unroll")                                                         \
    for (int im = 0; im < 2; ++im)                                            \
      _Pragma("unroll")                                                       \
      for (int k2 = 0; k2 < 2; ++k2) {                                        \
        const int row = wr * 64 + ((P) * 2 + im) * 16 + lc;                   \
        const int cb = k2 * 64 + lg * 16;                                     \
        af[im][k2] = *(const bf16x8*)(Ab + row * 128 + (cb ^ ((row & 7) << 4))); \
      }                                                                       \
  } while (0)
  #define MFMA_Q2(P) do {                                                     \
    __builtin_amdgcn_s_setprio(1);                                            \
    _Pragma("unroll")                                                         \
    for (int im = 0; im < 2; ++im)                                            \
      _Pragma("unroll")                                                       \
      for (int j = 0; j < 5; ++j)                                             \
        _Pragma("unroll")                                                     \
        for (int k2 = 0; k2 < 2; ++k2)                                        \
          acc[(P) * 2 + im][j] = __builtin_amdgcn_mfma_f32_16x16x32_bf16(     \
              af[im][k2], bfr[j][k2], acc[(P) * 2 + im][j], 0, 0, 0);         \
    __builtin_amdgcn_s_setprio(0);                                            \
  } while (0)
  #define LGKM0_BAR2() do {                                                   \
    asm volatile("s_waitcnt lgkmcnt(0)" ::: "memory");                        \
    __builtin_amdgcn_s_barrier();                                             \
    __builtin_amdgcn_sched_barrier(0);                                        \
  } while (0)

  const f32x4 zf = {0.f, 0.f, 0.f, 0.f};
  f32x4 acc[4][5];
  #pragma unroll
  for (int i = 0; i < 4; ++i)
    #pragma unroll
    for (int j = 0; j < 5; ++j) acc[i][j] = zf;

  // prologue: tiles 0 -> buf0, 1 -> buf1; vmcnt(7) leaves t1's 7 in flight
  STAGE_B5(0, 0); STAGE_A2P(0, 0);
  STAGE_B5(1, 1); STAGE_A2P(1, 1);
  asm volatile("s_waitcnt vmcnt(7)" ::: "memory");
  __builtin_amdgcn_s_barrier();
  __builtin_amdgcn_sched_barrier(0);

  for (int t = 0; t < NT; ++t) {
    const int cur = t & 1;
    const char* Ab = (const char*)&lds[cur][0];
    const char* Bb = Ab + 16384;
    int nk = t + 2; if (nk > NT - 1) nk = NT - 1;

    bf16x8 bfr[5][2], af[2][2];
    // P0: all B-frags + q0 A-frags; B region dead after -> stage B(t+2)
    #pragma unroll
    for (int j = 0; j < 5; ++j)
      #pragma unroll
      for (int k2 = 0; k2 < 2; ++k2) {
        const int row = wc * 80 + j * 16 + lc;
        const int cb = k2 * 64 + lg * 16;
        bfr[j][k2] = *(const bf16x8*)(Bb + row * 128 + (cb ^ ((row & 7) << 4)));
      }
    LOAD_AF2(0);
    LGKM0_BAR2();
    STAGE_B5(cur, nk);
    MFMA_Q2(0);
    // P1: q1 A-frags; A region dead after -> stage A(t+2)
    LOAD_AF2(1);
    LGKM0_BAR2();
    STAGE_A2P(cur, nk);
    MFMA_Q2(1);
    // tile end: t+1's 7 landed (t+2's 7 newest stay in flight)
    asm volatile("s_waitcnt vmcnt(7)" ::: "memory");
    __builtin_amdgcn_s_barrier();
    __builtin_amdgcn_sched_barrier(0);
  }
  #undef STAGE_B5
  #undef STAGE_A2P
  #undef LOAD_AF2
  #undef MFMA_Q2
  #undef LGKM0_BAR2

  #pragma unroll
  for (int i = 0; i < 4; ++i)
    #pragma unroll
    for (int j = 0; j < 5; ++j)
      #pragma unroll
      for (int r = 0; r < 4; ++r) {
        const int row = m0 + wr * 64 + i * 16 + lg * 4 + r;
        const int col = n0 + wc * 80 + j * 16 + lc;
        C[(size_t)row * ldc + col] = acc[i][j][r];
      }
}

// ---------------------------------------------------------------------------
// Fused RMSNorm + query-scale + RoPE. Reads qkv (T x 4096 bf16):
// cols [0,2048) = q (n-major), [2048,3072) = k, [3072,4096) = v.
__global__ __launch_bounds__(256) void fuse_norm_rope(
    const u16* __restrict__ qkv, const float* __restrict__ qnw, const float* __restrict__ knw,
    const int* __restrict__ pos, u16* __restrict__ qb, u16* __restrict__ kb,
    u16* __restrict__ vb, float* __restrict__ kvout)
{
  const int t = blockIdx.x;
  const int wave = threadIdx.x >> 6, lane = threadIdx.x & 63;
  const float p = (float)pos[t];
  const float kf = 0.10381025296523007f;  // log2(10000)/128
  float s0, c0, s1, c1;
  sincosf(p * exp2f(-(float)lane * kf), &s0, &c0);
  sincosf(p * exp2f(-(float)(lane + 64) * kf), &s1, &c1);
  const u16* row = qkv + (size_t)t * 4096;

  for (int pp = 0; pp < 4; ++pp) {
    const int hr = pp * 4 + wave;  // 0..7 q, 8..11 k, 12..15 v
    if (hr >= 12) {
      const int kk = hr - 12;
      const u16* src = row + 3072 + kk * 256;
      float* dstf = kvout + (size_t)T_TOK * NKV * HD + ((size_t)t * NKV + kk) * HD;
      u16*   dstb = vb + ((size_t)t * NKV + kk) * HD;
      #pragma unroll
      for (int q4 = 0; q4 < 4; ++q4) {
        const u16 s = src[lane + q4 * 64];
        dstf[lane + q4 * 64] = bf2f(s);
        dstb[lane + q4 * 64] = s;
      }
    } else {
      const bool isq = hr < 8;
      const int cb = isq ? hr * 256 : 2048 + (hr - 8) * 256;
      float v0 = bf2f(row[cb + lane]);
      float v1 = bf2f(row[cb + lane + 64]);
      float v2 = bf2f(row[cb + lane + 128]);
      float v3 = bf2f(row[cb + lane + 192]);
      float ss = v0 * v0 + v1 * v1 + v2 * v2 + v3 * v3;
      #pragma unroll
      for (int off = 1; off < 64; off <<= 1) ss += __shfl_xor(ss, off);
      float sc = rsqrtf(ss * (1.0f / 256.0f) + 1e-6f);
      if (isq) sc *= 0.0625f;  // QUERY_PRE_ATTN_SCALAR^-0.5
      const float* wn = isq ? qnw : knw;
      v0 *= sc * wn[lane];
      v1 *= sc * wn[lane + 64];
      v2 *= sc * wn[lane + 128];
      v3 *= sc * wn[lane + 192];
      const float n0 = v0 * c0 - v2 * s0;
      const float n2 = v2 * c0 + v0 * s0;
      const float n1 = v1 * c1 - v3 * s1;
      const float n3 = v3 * c1 + v1 * s1;
      if (isq) {
        u16* dst = qb + (size_t)t * 2048 + hr * 256;
        dst[lane]       = f2bf(n0);
        dst[lane + 64]  = f2bf(n1);
        dst[lane + 128] = f2bf(n2);
        dst[lane + 192] = f2bf(n3);
      } else {
        const int kk = hr - 8;
        float* dstf = kvout + ((size_t)t * NKV + kk) * HD;
        dstf[lane]       = n0;
        dstf[lane + 64]  = n1;
        dstf[lane + 128] = n2;
        dstf[lane + 192] = n3;
        u16* dstb = kb + ((size_t)t * NKV + kk) * HD;
        dstb[lane]       = f2bf(n0);
        dstb[lane + 64]  = f2bf(n1);
        dstb[lane + 128] = f2bf(n2);
        dstb[lane + 192] = f2bf(n3);
      }
    }
  }
}

// ---------------------------------------------------------------------------
// Per-head V transpose: vb (T x NKV x HD bf16) -> vt (NKV x HD x T bf16).
// 16B vectorized loads and stores (padded LDS tile).
__global__ __launch_bounds__(256) void transpose_v(
    const u16* __restrict__ vc, u16* __restrict__ vt)
{
  __shared__ u16 tile[64][72];
  const int kk = blockIdx.z;
  const int t0 = blockIdx.y * 64, h0 = blockIdx.x * 64;
  const int lr = threadIdx.x >> 3, ch = threadIdx.x & 7;
  #pragma unroll
  for (int h = 0; h < 2; ++h) {
    const int row = lr + h * 32;  // token index within tile
    *(bf16x8*)&tile[row][ch * 8] =
        *(const bf16x8*)&vc[((size_t)(t0 + row) * NKV + kk) * HD + h0 + ch * 8];
  }
  __syncthreads();
  #pragma unroll
  for (int h = 0; h < 2; ++h) {
    const int hc = lr + h * 32;   // head-dim index within tile
    bf16x8 v;
    #pragma unroll
    for (int j = 0; j < 8; ++j) v[j] = (short)tile[ch * 8 + j][hc];
    *(bf16x8*)&vt[(size_t)kk * HD * T_TOK + (size_t)(h0 + hc) * T_TOK + t0 + ch * 8] = v;
  }
}

// ---------------------------------------------------------------------------
// Flash attention v5: 2 q-heads per block (one kv head), double-buffered
// global_load_lds K/V staging, wave-local softmax, per-wave private P slice,
// one barrier per tile. LDS 144 KB -> 1 block/CU, 8 waves.
__global__ __launch_bounds__(512, 1) void attn_kernel(
    const u16* __restrict__ qb, const u16* __restrict__ kc,
    const u16* __restrict__ vt, u16* __restrict__ ob)
{
  __shared__ __align__(16) u16 Ks[2][64 * 256];    // [buf][key][d] swz
  __shared__ __align__(16) u16 Vts[2][256 * 64];   // [buf][d][key] swz
  __shared__ __align__(16) u16 Ps[8][16 * 64];     // per-wave [qrow][key] swz

  const int kk = blockIdx.y;             // kv head
  const int t0 = blockIdx.x * 64;
  const int tid = threadIdx.x;
  const int wave = tid >> 6, lane = tid & 63;
  const int lg = lane >> 4, lc = lane & 15;
  const int hq = kk * 2 + (wave >> 2);   // q head for this wave
  const int wrow = (wave & 3) * 16;      // q-row base within 64-row block
  const int lswz = (lc & 7) << 4;
  const f32x4 zf = {0.f, 0.f, 0.f, 0.f};

  const int lrowK = tid >> 5;                        // 0..15
  const int scolK = ((tid & 31) * 16) ^ ((lrowK & 7) << 4);
  const int lrowV = tid >> 3;                        // 0..63
  const int scolV = ((tid & 7) * 16) ^ ((lrowV & 7) << 4);

  #define STAGEKV(KT, BUF) do {                                                \
    const int kb_ = (KT) * 64;                                                 \
    const u16* kp_ = kc + (size_t)(kb_ + lrowK) * (NKV * HD) + kk * HD + (scolK >> 1); \
    _Pragma("unroll")                                                          \
    for (int is = 0; is < 4; ++is)                                             \
      async_cp16(kp_ + (size_t)(is * 16) * (NKV * HD),                         \
                 (char*)&Ks[BUF][0] + is * 8192 + wave * 1024);                \
    const u16* vp_ = vt + (size_t)kk * (HD * T_TOK) + (size_t)lrowV * T_TOK + kb_ + (scolV >> 1); \
    _Pragma("unroll")                                                          \
    for (int is = 0; is < 4; ++is)                                             \
      async_cp16(vp_ + (size_t)(is * 64) * T_TOK,                              \
                 (char*)&Vts[BUF][0] + is * 8192 + wave * 1024);               \
  } while (0)

  bf16x8 qf[8];
  {
    const u16* qp = qb + (size_t)(t0 + wrow + lc) * 2048 + hq * 256 + lg * 8;
    #pragma unroll
    for (int ks = 0; ks < 8; ++ks) qf[ks] = *(const bf16x8*)(qp + ks * 32);
  }

  f32x4 o_acc[16];
  #pragma unroll
  for (int j = 0; j < 16; ++j) o_acc[j] = zf;
  float m_r[4], l_r[4];
  #pragma unroll
  for (int r = 0; r < 4; ++r) { m_r[r] = -1e30f; l_r[r] = 0.f; }

  const int mtile = t0 >> 6;
  const int ktf = (mtile >= 16) ? (mtile - 16) : 0;

  STAGEKV(ktf, 0);
  __syncthreads();

  int cur = 0;
  for (int kt = ktf; kt <= mtile; ++kt) {
    const int kb = kt * 64;
    if (kt < mtile) STAGEKV(kt + 1, cur ^ 1);

    const u16* Kb = &Ks[cur][0];
    const u16* Vb = &Vts[cur][0];

    f32x4 sf[4];
    #pragma unroll
    for (int j = 0; j < 4; ++j) sf[j] = zf;
    __builtin_amdgcn_s_setprio(1);
    #pragma unroll
    for (int ks = 0; ks < 8; ++ks)
      #pragma unroll
      for (int j = 0; j < 4; ++j) {
        const int row = j * 16 + lc;
        bf16x8 kf = *(const bf16x8*)((const char*)Kb + ((row * 512 + ks * 64 + lg * 16) ^ lswz));
        sf[j] = __builtin_amdgcn_mfma_f32_16x16x32_bf16(qf[ks], kf, sf[j], 0, 0, 0);
      }
    __builtin_amdgcn_s_setprio(0);

    const bool interior = (kb >= t0 - 960) && (kb <= t0 - 64);
    if (!interior) {
      #pragma unroll
      for (int j = 0; j < 4; ++j) {
        const int gcol = kb + j * 16 + lc;
        #pragma unroll
        for (int r = 0; r < 4; ++r) {
          const int grow = t0 + wrow + lg * 4 + r;
          if ((unsigned)(grow - gcol) >= WIN) sf[j][r] = -1e30f;
        }
      }
    }

    float a_r[4];
    #pragma unroll
    for (int r = 0; r < 4; ++r) {
      float v = fmaxf(fmaxf(sf[0][r], sf[1][r]), fmaxf(sf[2][r], sf[3][r]));
      v = fmaxf(v, __shfl_xor(v, 1));
      v = fmaxf(v, __shfl_xor(v, 2));
      v = fmaxf(v, __shfl_xor(v, 4));
      v = fmaxf(v, __shfl_xor(v, 8));
      const float mn = fmaxf(m_r[r], v);
      a_r[r] = __expf(m_r[r] - mn);
      m_r[r] = mn;
    }

    char* myP = (char*)&Ps[wave][0];
    #pragma unroll
    for (int r = 0; r < 4; ++r) {
      const int row = lg * 4 + r;
      const int rsw = (row & 7) << 4;
      float su = 0.f;
      #pragma unroll
      for (int j = 0; j < 4; ++j) {
        const float p = __expf(sf[j][r] - m_r[r]);
        su += p;
        *(u16*)(myP + ((row * 128 + (j * 16 + lc) * 2) ^ rsw)) = f2bf(p);
      }
      su += __shfl_xor(su, 1);
      su += __shfl_xor(su, 2);
      su += __shfl_xor(su, 4);
      su += __shfl_xor(su, 8);
      l_r[r] = l_r[r] * a_r[r] + su;
    }

    #pragma unroll
    for (int j = 0; j < 16; ++j) {
      o_acc[j][0] *= a_r[0];
      o_acc[j][1] *= a_r[1];
      o_acc[j][2] *= a_r[2];
      o_acc[j][3] *= a_r[3];
    }

    bf16x8 pa[2];
    #pragma unroll
    for (int ks = 0; ks < 2; ++ks)
      pa[ks] = *(const bf16x8*)(myP + ((lc * 128 + ks * 64 + lg * 16) ^ lswz));
    __builtin_amdgcn_s_setprio(1);
    #pragma unroll
    for (int ks = 0; ks < 2; ++ks)
      #pragma unroll
      for (int j = 0; j < 16; ++j) {
        const int row = j * 16 + lc;
        bf16x8 vf = *(const bf16x8*)((const char*)Vb + ((row * 128 + ks * 64 + lg * 16) ^ lswz));
        o_acc[j] = __builtin_amdgcn_mfma_f32_16x16x32_bf16(pa[ks], vf, o_acc[j], 0, 0, 0);
      }
    __builtin_amdgcn_s_setprio(0);

    __syncthreads();
    cur ^= 1;
  }
  #undef STAGEKV

  #pragma unroll
  for (int r = 0; r < 4; ++r) {
    const float li = 1.f / l_r[r];
    const size_t rowb = (size_t)(t0 + wrow + lg * 4 + r) * 2048 + hq * 256 + lc;
    #pragma unroll
    for (int j = 0; j < 16; ++j)
      ob[rowb + j * 16] = f2bf(o_acc[j][r] * li);
  }
}

// ---------------------------------------------------------------------------
extern "C" void kernel_launch(void* const* d_in, const int* in_sizes, int n_in,
                              void* d_out, int out_size, void* d_ws, size_t ws_size,
                              hipStream_t stream)
{
  (void)in_sizes; (void)n_in; (void)out_size; (void)ws_size;
  const float* x   = (const float*)d_in[0];
  const float* wq  = (const float*)d_in[1];
  const float* wk  = (const float*)d_in[2];
  const float* wv  = (const float*)d_in[3];
  const float* wo  = (const float*)d_in[4];
  const float* qnw = (const float*)d_in[5];
  const float* knw = (const float*)d_in[6];
  const int*   pos = (const int*)d_in[7];
  float* out = (float*)d_out;  // f32: [2*T*NKV*HD kv cache][T*DM o]

  // workspace layout (peak 86 MB), lifetime-aliased
  char* ws = (char*)d_ws;
  u16* woT   = (u16*)(ws);                    // 2560x2048 bf16 (10.5 MB), live to end
  u16* xb    = (u16*)(ws + 10485760);         // T x DM bf16 (21.0 MB)
  u16* wqkvT = (u16*)(ws + 31457280);         // 4096 x DM bf16 (21.0 MB)
  u16* qkv   = (u16*)(ws + 52428800);         // T x 4096 bf16 (33.6 MB)
  u16* q_b   = xb;                            // alias: xb dead after gemm1 (16.8 MB)
  u16* kb    = wqkvT;                         // alias: wqkvT dead after gemm1 (8.4 MB)
  u16* vb    = (u16*)(ws + 31457280 + 8388608); // (8.4 MB, still inside wqkvT)
  u16* vtb   = qkv;                           // alias: qkv dead after fuse (8.4 MB)
  u16* attn  = (u16*)(ws + 52428800 + 8388608); // (16.8 MB, inside qkv region)

  convert_f32_bf16<<<1024, 256, 0, stream>>>(x, xb, T_TOK * DM);
  transpose_f32_bf16<<<dim3(32, 40), 256, 0, stream>>>(wq, wqkvT, DM, 2048);
  transpose_f32_bf16<<<dim3(16, 40), 256, 0, stream>>>(wk, wqkvT + 2048 * DM, DM, 1024);
  transpose_f32_bf16<<<dim3(16, 40), 256, 0, stream>>>(wv, wqkvT + 3072 * DM, DM, 1024);
  transpose_f32_bf16<<<dim3(40, 32), 256, 0, stream>>>(wo, woT, 2048, DM);

  // QKV projection: 256x256 tile, phase-interleaved schedule, 256 blocks
  gemm256p<false><<<256, 512, 0, stream>>>(xb, wqkvT, qkv, DM, DM, DM, 4096);

  // RMSNorm + scale + RoPE; k/v f32 into kv cache (d_out) + bf16 copies
  fuse_norm_rope<<<T_TOK, 256, 0, stream>>>(qkv, qnw, knw, pos, q_b, kb, vb, out);

  // V^T per head for PV MFMA B-operand
  transpose_v<<<dim3(4, 64, 4), 256, 0, stream>>>(vb, vtb);

  // flash attention: 64-row q-block x kv-head (2 q heads) -> attn (T x 2048)
  attn_kernel<<<dim3(64, 4), 512, 0, stream>>>(q_b, kb, vtb, attn);

  // output projection: 128x320 tile, progressive schedule, 256 blocks
  gemm_p2<<<256, 512, 0, stream>>>(attn, woT, out + 2 * (size_t)T_TOK * NKV * HD,
                                   2048, 2048, 2048, DM);
}